// Round 1
// baseline (1348.459 us; speedup 1.0000x reference)
//
#include <hip/hip_runtime.h>
#include <hip/hip_bf16.h>
#include <math.h>

#define NEG_SLOPE 0.2f

__device__ __forceinline__ float leaky(float x){ return x > 0.f ? x : NEG_SLOPE*x; }
__device__ __forceinline__ float elu(float x){ return x > 0.f ? x : expm1f(x); }

// ---------- CSR build ----------
__global__ __launch_bounds__(256) void k_degree(const int* __restrict__ ei, int E, int* __restrict__ deg){
  int e = blockIdx.x*256 + threadIdx.x;
  if (e >= E) return;
  atomicAdd(&deg[ei[E + e]], 1);
}

__global__ __launch_bounds__(256) void k_chunk_sum(const int* __restrict__ deg, int n, int* __restrict__ cs){
  __shared__ int s[256];
  int base = blockIdx.x*1024;
  int sum = 0;
  for (int i = threadIdx.x; i < 1024; i += 256){
    int idx = base + i;
    if (idx < n) sum += deg[idx];
  }
  s[threadIdx.x] = sum; __syncthreads();
  for (int st = 128; st > 0; st >>= 1){
    if (threadIdx.x < st) s[threadIdx.x] += s[threadIdx.x + st];
    __syncthreads();
  }
  if (threadIdx.x == 0) cs[blockIdx.x] = s[0];
}

__global__ void k_scan_chunks(int* __restrict__ cs, int nchunks, int* __restrict__ total_out){
  if (threadIdx.x || blockIdx.x) return;
  int run = 0;
  for (int i = 0; i < nchunks; i++){ int v = cs[i]; cs[i] = run; run += v; }
  *total_out = run;   // offsets[N]
}

__global__ __launch_bounds__(256) void k_scan_within(const int* __restrict__ deg, const int* __restrict__ cs,
                              int n, int* __restrict__ offsets, int* __restrict__ cursor){
  __shared__ int s[256];
  int tid = threadIdx.x;
  int base = blockIdx.x*1024;
  int v[4]; int local = 0;
  #pragma unroll
  for (int i = 0; i < 4; i++){
    int idx = base + tid*4 + i;
    v[i] = (idx < n) ? deg[idx] : 0;
    local += v[i];
  }
  s[tid] = local; __syncthreads();
  for (int st = 1; st < 256; st <<= 1){
    int val = (tid >= st) ? s[tid - st] : 0;
    __syncthreads();
    s[tid] += val;
    __syncthreads();
  }
  int run = (tid ? s[tid-1] : 0) + cs[blockIdx.x];
  #pragma unroll
  for (int i = 0; i < 4; i++){
    int idx = base + tid*4 + i;
    if (idx < n){ offsets[idx] = run; cursor[idx] = run; run += v[i]; }
  }
}

__global__ __launch_bounds__(256) void k_scatter(const int* __restrict__ ei, int E,
                          int* __restrict__ cursor, int* __restrict__ csr_src){
  int e = blockIdx.x*256 + threadIdx.x;
  if (e >= E) return;
  int s = ei[e], d = ei[E + e];
  int pos = atomicAdd(&cursor[d], 1);
  csr_src[pos] = s;
}

// ---------- GEMM: Y[n,M] = X[n,128] @ W[128,M] ----------
__global__ __launch_bounds__(256) void k_gemm(const float* __restrict__ X, const float* __restrict__ W,
                     float* __restrict__ Y, int n, int M){
  __shared__ float xs[128][65];           // [k][r], +1 pad: conflict-free
  int rowBase = blockIdx.x*64;
  int cBase = blockIdx.y*64;
  int tid = threadIdx.x;
  for (int idx = tid; idx < 64*128; idx += 256){
    int r = idx >> 7, k = idx & 127;
    int row = rowBase + r;
    xs[k][r] = (row < n) ? X[(size_t)row*128 + k] : 0.f;
  }
  __syncthreads();
  int tr = tid >> 4, tc = tid & 15;
  int r0 = tr*4;
  int c0 = cBase + tc*4;
  float acc[4][4] = {};
  if (c0 < M){
    for (int k = 0; k < 128; k++){
      float4 wv = *(const float4*)(W + (size_t)k*M + c0);
      float x0 = xs[k][r0+0], x1 = xs[k][r0+1], x2 = xs[k][r0+2], x3 = xs[k][r0+3];
      acc[0][0] += x0*wv.x; acc[0][1] += x0*wv.y; acc[0][2] += x0*wv.z; acc[0][3] += x0*wv.w;
      acc[1][0] += x1*wv.x; acc[1][1] += x1*wv.y; acc[1][2] += x1*wv.z; acc[1][3] += x1*wv.w;
      acc[2][0] += x2*wv.x; acc[2][1] += x2*wv.y; acc[2][2] += x2*wv.z; acc[2][3] += x2*wv.w;
      acc[3][0] += x3*wv.x; acc[3][1] += x3*wv.y; acc[3][2] += x3*wv.z; acc[3][3] += x3*wv.w;
    }
    #pragma unroll
    for (int i = 0; i < 4; i++){
      int row = rowBase + r0 + i;
      if (row < n){
        float4 o = make_float4(acc[i][0], acc[i][1], acc[i][2], acc[i][3]);
        *(float4*)(Y + (size_t)row*M + c0) = o;
      }
    }
  }
}

// ---------- attention coefficients ----------
__global__ __launch_bounds__(256) void k_attn(const float* __restrict__ Hb, const float* __restrict__ a_s,
                     const float* __restrict__ a_d, float* __restrict__ asrc, float* __restrict__ adst,
                     int n, int H, int M){
  int idx = blockIdx.x*256 + threadIdx.x;
  if (idx >= n*H) return;
  int node = idx / H, h = idx - node*H;
  const float* row = Hb + (size_t)node*M + h*32;
  const float* as = a_s + h*32;
  const float* ad = a_d + h*32;
  float s1 = 0.f, s2 = 0.f;
  #pragma unroll
  for (int c = 0; c < 32; c++){ float v = row[c]; s1 += v*as[c]; s2 += v*ad[c]; }
  asrc[idx] = s1; adst[idx] = s2;
}

// ---------- per-dst softmax-weighted aggregation + bias + ELU ----------
template<int HC>
__global__ __launch_bounds__(256) void k_agg(const float* __restrict__ Hb, const float* __restrict__ asrc,
                    const float* __restrict__ adst, const int* __restrict__ offsets,
                    const int* __restrict__ csr_src, const float* __restrict__ bias,
                    float* __restrict__ Out, int n){
  constexpr int H = HC/32;
  int gid = blockIdx.x*256 + threadIdx.x;
  int wave = gid >> 6;
  int lane = threadIdx.x & 63;
  int node, ch0;
  if (HC == 128){ node = wave;                  ch0 = lane;      }
  else          { node = wave*2 + (lane >> 5);  ch0 = lane & 31; }
  if (node >= n) return;
  const int h0 = ch0 >> 5;               // head for ch0 (0/1 when HC=128)
  float ad0 = adst[node*H + h0];
  float ad1 = 0.f;
  if (HC == 128) ad1 = adst[node*H + h0 + 2];
  float acc0 = 0.f, acc1 = 0.f, den0 = 0.f, den1 = 0.f;
  // self loop (GATConv adds one per node)
  {
    float w0 = __expf(leaky(asrc[node*H + h0] + ad0));
    den0 += w0; acc0 += w0 * Hb[(size_t)node*HC + ch0];
    if (HC == 128){
      float w1 = __expf(leaky(asrc[node*H + h0 + 2] + ad1));
      den1 += w1; acc1 += w1 * Hb[(size_t)node*HC + ch0 + 64];
    }
  }
  int j = offsets[node], end = offsets[node+1];
  for (; j < end; j++){
    int s = csr_src[j];
    float w0 = __expf(leaky(asrc[s*H + h0] + ad0));
    den0 += w0; acc0 += w0 * Hb[(size_t)s*HC + ch0];
    if (HC == 128){
      float w1 = __expf(leaky(asrc[s*H + h0 + 2] + ad1));
      den1 += w1; acc1 += w1 * Hb[(size_t)s*HC + ch0 + 64];
    }
  }
  float v0 = acc0/(den0 + 1e-16f) + bias[ch0];
  Out[(size_t)node*HC + ch0] = elu(v0);
  if (HC == 128){
    float v1 = acc1/(den1 + 1e-16f) + bias[ch0 + 64];
    Out[(size_t)node*HC + ch0 + 64] = elu(v1);
  }
}

// ---------- readout ----------
__global__ __launch_bounds__(256) void k_pool(const float* __restrict__ H3, const int* __restrict__ batch,
                     float* __restrict__ pool, float* __restrict__ cnt, int n){
  int idx = blockIdx.x*256 + threadIdx.x;
  if (idx >= n*32) return;
  int node = idx >> 5, c = idx & 31;
  int b = batch[node];
  atomicAdd(&pool[b*32 + c], H3[idx]);
  if (c == 0) atomicAdd(&cnt[b], 1.0f);
}

__global__ void k_out(const float* __restrict__ pool, const float* __restrict__ cnt,
                      const float* __restrict__ fc_w, const float* __restrict__ fc_b,
                      float* __restrict__ out, int G){
  int g = blockIdx.x*blockDim.x + threadIdx.x;
  if (g >= G) return;
  float c = cnt[g]; if (c < 1.f) c = 1.f;
  float s = 0.f;
  #pragma unroll
  for (int i = 0; i < 32; i++) s += pool[g*32 + i]*fc_w[i];
  out[g] = s/c + fc_b[0];
}

extern "C" void kernel_launch(void* const* d_in, const int* in_sizes, int n_in,
                              void* d_out, int out_size, void* d_ws, size_t ws_size,
                              hipStream_t stream){
  const float* x    = (const float*)d_in[0];
  const int*   ei   = (const int*)d_in[1];
  const int*   batch= (const int*)d_in[2];
  const float* W1   = (const float*)d_in[3];
  const float* as1  = (const float*)d_in[4];
  const float* ad1  = (const float*)d_in[5];
  const float* b1   = (const float*)d_in[6];
  const float* W2   = (const float*)d_in[7];
  const float* as2  = (const float*)d_in[8];
  const float* ad2  = (const float*)d_in[9];
  const float* b2   = (const float*)d_in[10];
  const float* W3   = (const float*)d_in[11];
  const float* as3  = (const float*)d_in[12];
  const float* ad3  = (const float*)d_in[13];
  const float* b3   = (const float*)d_in[14];
  const float* fcw  = (const float*)d_in[15];
  const float* fcb  = (const float*)d_in[16];
  float* out = (float*)d_out;

  const int N = in_sizes[0] / 128;
  const int E = in_sizes[1] / 2;
  const int G = out_size;

  char* p = (char*)d_ws;
  auto alloc = [&](size_t bytes) -> void* {
    void* r = (void*)p;
    p += (bytes + 255) & ~(size_t)255;
    return r;
  };
  float* bufA   = (float*)alloc((size_t)N*128*sizeof(float));
  float* bufB   = (float*)alloc((size_t)N*128*sizeof(float));
  float* asrc   = (float*)alloc((size_t)N*4*sizeof(float));
  float* adst   = (float*)alloc((size_t)N*4*sizeof(float));
  int*   deg    = (int*)alloc((size_t)N*sizeof(int));
  int*   offsets= (int*)alloc((size_t)(N+1)*sizeof(int));
  int*   cursor = (int*)alloc((size_t)N*sizeof(int));
  int*   csr    = (int*)alloc((size_t)E*sizeof(int));
  int*   csums  = (int*)alloc(1024*sizeof(int));
  float* pool   = (float*)alloc((size_t)G*32*sizeof(float));
  float* cnt    = (float*)alloc((size_t)G*sizeof(float));

  const int nchunks = (N + 1023)/1024;

  hipMemsetAsync(deg, 0, (size_t)N*sizeof(int), stream);
  hipMemsetAsync(pool, 0, (size_t)G*32*sizeof(float), stream);
  hipMemsetAsync(cnt, 0, (size_t)G*sizeof(float), stream);

  k_degree<<<(E+255)/256, 256, 0, stream>>>(ei, E, deg);
  k_chunk_sum<<<nchunks, 256, 0, stream>>>(deg, N, csums);
  k_scan_chunks<<<1, 1, 0, stream>>>(csums, nchunks, offsets + N);
  k_scan_within<<<nchunks, 256, 0, stream>>>(deg, csums, N, offsets, cursor);
  k_scatter<<<(E+255)/256, 256, 0, stream>>>(ei, E, cursor, csr);

  dim3 g12((N+63)/64, 2);
  // layer 1
  k_gemm<<<g12, 256, 0, stream>>>(x, W1, bufB, N, 128);
  k_attn<<<(N*4+255)/256, 256, 0, stream>>>(bufB, as1, ad1, asrc, adst, N, 4, 128);
  k_agg<128><<<((size_t)N*64+255)/256, 256, 0, stream>>>(bufB, asrc, adst, offsets, csr, b1, bufA, N);
  // layer 2
  k_gemm<<<g12, 256, 0, stream>>>(bufA, W2, bufB, N, 128);
  k_attn<<<(N*4+255)/256, 256, 0, stream>>>(bufB, as2, ad2, asrc, adst, N, 4, 128);
  k_agg<128><<<((size_t)N*64+255)/256, 256, 0, stream>>>(bufB, asrc, adst, offsets, csr, b2, bufA, N);
  // layer 3
  dim3 g3((N+63)/64, 1);
  k_gemm<<<g3, 256, 0, stream>>>(bufA, W3, bufB, N, 32);
  k_attn<<<(N+255)/256, 256, 0, stream>>>(bufB, as3, ad3, asrc, adst, N, 1, 32);
  long long waves3 = (N + 1)/2;
  k_agg<32><<<(int)((waves3*64 + 255)/256), 256, 0, stream>>>(bufB, asrc, adst, offsets, csr, b3, bufA, N);
  // readout
  k_pool<<<(N*32+255)/256, 256, 0, stream>>>(bufA, batch, pool, cnt, N);
  k_out<<<(G+255)/256, 256, 0, stream>>>(pool, cnt, fcw, fcb, out, G);
}

// Round 2
// 1086.437 us; speedup vs baseline: 1.2412x; 1.2412x over previous
//
#include <hip/hip_runtime.h>
#include <hip/hip_bf16.h>
#include <math.h>

#define NEG_SLOPE 0.2f

__device__ __forceinline__ float leaky(float x){ return x > 0.f ? x : NEG_SLOPE*x; }
__device__ __forceinline__ float elu(float x){ return x > 0.f ? x : expm1f(x); }

// ---------- CSR build ----------
__global__ __launch_bounds__(256) void k_degree(const int* __restrict__ ei, int E, int* __restrict__ deg){
  int e = blockIdx.x*256 + threadIdx.x;
  if (e >= E) return;
  atomicAdd(&deg[ei[E + e]], 1);
}

__global__ __launch_bounds__(256) void k_chunk_sum(const int* __restrict__ deg, int n, int* __restrict__ cs){
  __shared__ int s[256];
  int base = blockIdx.x*1024;
  int sum = 0;
  for (int i = threadIdx.x; i < 1024; i += 256){
    int idx = base + i;
    if (idx < n) sum += deg[idx];
  }
  s[threadIdx.x] = sum; __syncthreads();
  for (int st = 128; st > 0; st >>= 1){
    if (threadIdx.x < st) s[threadIdx.x] += s[threadIdx.x + st];
    __syncthreads();
  }
  if (threadIdx.x == 0) cs[blockIdx.x] = s[0];
}

__global__ void k_scan_chunks(int* __restrict__ cs, int nchunks, int* __restrict__ total_out){
  if (threadIdx.x || blockIdx.x) return;
  int run = 0;
  for (int i = 0; i < nchunks; i++){ int v = cs[i]; cs[i] = run; run += v; }
  *total_out = run;   // offsets[N]
}

__global__ __launch_bounds__(256) void k_scan_within(const int* __restrict__ deg, const int* __restrict__ cs,
                              int n, int* __restrict__ offsets, int* __restrict__ cursor){
  __shared__ int s[256];
  int tid = threadIdx.x;
  int base = blockIdx.x*1024;
  int v[4]; int local = 0;
  #pragma unroll
  for (int i = 0; i < 4; i++){
    int idx = base + tid*4 + i;
    v[i] = (idx < n) ? deg[idx] : 0;
    local += v[i];
  }
  s[tid] = local; __syncthreads();
  for (int st = 1; st < 256; st <<= 1){
    int val = (tid >= st) ? s[tid - st] : 0;
    __syncthreads();
    s[tid] += val;
    __syncthreads();
  }
  int run = (tid ? s[tid-1] : 0) + cs[blockIdx.x];
  #pragma unroll
  for (int i = 0; i < 4; i++){
    int idx = base + tid*4 + i;
    if (idx < n){ offsets[idx] = run; cursor[idx] = run; run += v[i]; }
  }
}

__global__ __launch_bounds__(256) void k_scatter(const int* __restrict__ ei, int E,
                          int* __restrict__ cursor, int* __restrict__ csr_src){
  int e = blockIdx.x*256 + threadIdx.x;
  if (e >= E) return;
  int s = ei[e], d = ei[E + e];
  int pos = atomicAdd(&cursor[d], 1);
  csr_src[pos] = s;
}

// ---------- GEMM: Y[n,M] = X[n,128] @ W[128,M] ----------
__global__ __launch_bounds__(256) void k_gemm(const float* __restrict__ X, const float* __restrict__ W,
                     float* __restrict__ Y, int n, int M){
  __shared__ float xs[128][65];           // [k][r], +1 pad: conflict-free
  int rowBase = blockIdx.x*64;
  int cBase = blockIdx.y*64;
  int tid = threadIdx.x;
  for (int idx = tid; idx < 64*128; idx += 256){
    int r = idx >> 7, k = idx & 127;
    int row = rowBase + r;
    xs[k][r] = (row < n) ? X[(size_t)row*128 + k] : 0.f;
  }
  __syncthreads();
  int tr = tid >> 4, tc = tid & 15;
  int r0 = tr*4;
  int c0 = cBase + tc*4;
  float acc[4][4] = {};
  if (c0 < M){
    for (int k = 0; k < 128; k++){
      float4 wv = *(const float4*)(W + (size_t)k*M + c0);
      float x0 = xs[k][r0+0], x1 = xs[k][r0+1], x2 = xs[k][r0+2], x3 = xs[k][r0+3];
      acc[0][0] += x0*wv.x; acc[0][1] += x0*wv.y; acc[0][2] += x0*wv.z; acc[0][3] += x0*wv.w;
      acc[1][0] += x1*wv.x; acc[1][1] += x1*wv.y; acc[1][2] += x1*wv.z; acc[1][3] += x1*wv.w;
      acc[2][0] += x2*wv.x; acc[2][1] += x2*wv.y; acc[2][2] += x2*wv.z; acc[2][3] += x2*wv.w;
      acc[3][0] += x3*wv.x; acc[3][1] += x3*wv.y; acc[3][2] += x3*wv.z; acc[3][3] += x3*wv.w;
    }
    #pragma unroll
    for (int i = 0; i < 4; i++){
      int row = rowBase + r0 + i;
      if (row < n){
        float4 o = make_float4(acc[i][0], acc[i][1], acc[i][2], acc[i][3]);
        *(float4*)(Y + (size_t)row*M + c0) = o;
      }
    }
  }
}

// ---------- attention coefficients ----------
__global__ __launch_bounds__(256) void k_attn(const float* __restrict__ Hb, const float* __restrict__ a_s,
                     const float* __restrict__ a_d, float* __restrict__ asrc, float* __restrict__ adst,
                     int n, int H, int M){
  int idx = blockIdx.x*256 + threadIdx.x;
  if (idx >= n*H) return;
  int node = idx / H, h = idx - node*H;
  const float* row = Hb + (size_t)node*M + h*32;
  const float* as = a_s + h*32;
  const float* ad = a_d + h*32;
  float s1 = 0.f, s2 = 0.f;
  #pragma unroll
  for (int c = 0; c < 32; c++){ float v = row[c]; s1 += v*as[c]; s2 += v*ad[c]; }
  asrc[idx] = s1; adst[idx] = s2;
}

// ---------- per-dst softmax-weighted aggregation + bias + ELU ----------
template<int HC>
__global__ __launch_bounds__(256) void k_agg(const float* __restrict__ Hb, const float* __restrict__ asrc,
                    const float* __restrict__ adst, const int* __restrict__ offsets,
                    const int* __restrict__ csr_src, const float* __restrict__ bias,
                    float* __restrict__ Out, int n){
  constexpr int H = HC/32;
  int gid = blockIdx.x*256 + threadIdx.x;
  int wave = gid >> 6;
  int lane = threadIdx.x & 63;
  int node, ch0;
  if (HC == 128){ node = wave;                  ch0 = lane;      }
  else          { node = wave*2 + (lane >> 5);  ch0 = lane & 31; }
  if (node >= n) return;
  const int h0 = ch0 >> 5;               // head for ch0 (0/1 when HC=128)
  float ad0 = adst[node*H + h0];
  float ad1 = 0.f;
  if (HC == 128) ad1 = adst[node*H + h0 + 2];
  float acc0 = 0.f, acc1 = 0.f, den0 = 0.f, den1 = 0.f;
  // self loop (GATConv adds one per node)
  {
    float w0 = __expf(leaky(asrc[node*H + h0] + ad0));
    den0 += w0; acc0 += w0 * Hb[(size_t)node*HC + ch0];
    if (HC == 128){
      float w1 = __expf(leaky(asrc[node*H + h0 + 2] + ad1));
      den1 += w1; acc1 += w1 * Hb[(size_t)node*HC + ch0 + 64];
    }
  }
  int j = offsets[node], end = offsets[node+1];
  for (; j < end; j++){
    int s = csr_src[j];
    float w0 = __expf(leaky(asrc[s*H + h0] + ad0));
    den0 += w0; acc0 += w0 * Hb[(size_t)s*HC + ch0];
    if (HC == 128){
      float w1 = __expf(leaky(asrc[s*H + h0 + 2] + ad1));
      den1 += w1; acc1 += w1 * Hb[(size_t)s*HC + ch0 + 64];
    }
  }
  float v0 = acc0/(den0 + 1e-16f) + bias[ch0];
  Out[(size_t)node*HC + ch0] = elu(v0);
  if (HC == 128){
    float v1 = acc1/(den1 + 1e-16f) + bias[ch0 + 64];
    Out[(size_t)node*HC + ch0 + 64] = elu(v1);
  }
}

// ---------- readout: graph boundaries from sorted batch, then pool+fc fused ----------
__global__ __launch_bounds__(256) void k_bounds(const int* __restrict__ batch, int n, int G,
                                                int* __restrict__ gstart){
  int i = blockIdx.x*256 + threadIdx.x;
  if (i >= n) return;
  int b = batch[i];
  int bp = (i > 0) ? batch[i-1] : -1;
  for (int g = bp + 1; g <= b; g++) gstart[g] = i;     // first node of graph g
  if (i == n-1){
    for (int g = b + 1; g <= G; g++) gstart[g] = n;    // tail (incl. gstart[G]=N)
  }
}

__global__ __launch_bounds__(256) void k_pool2(const float* __restrict__ H3,
                     const int* __restrict__ gstart, const float* __restrict__ fcw,
                     const float* __restrict__ fcb, float* __restrict__ out, int G){
  int g = blockIdx.x;
  int s0 = gstart[g], s1 = gstart[g+1];
  int tid = threadIdx.x;
  int c = tid & 31, r = tid >> 5;                      // 8 row-lanes x 32 channels
  float sum = 0.f;
  for (int i = s0 + r; i < s1; i += 8)
    sum += H3[(size_t)i*32 + c];
  __shared__ float sh[8][32];
  sh[r][c] = sum;
  __syncthreads();
  if (tid < 32){
    float t = 0.f;
    #pragma unroll
    for (int k = 0; k < 8; k++) t += sh[k][tid];
    t *= fcw[tid];
    #pragma unroll
    for (int off = 16; off; off >>= 1) t += __shfl_down(t, off, 32);
    if (tid == 0){
      float cnt = (float)(s1 - s0); if (cnt < 1.f) cnt = 1.f;
      out[g] = t/cnt + fcb[0];
    }
  }
}

extern "C" void kernel_launch(void* const* d_in, const int* in_sizes, int n_in,
                              void* d_out, int out_size, void* d_ws, size_t ws_size,
                              hipStream_t stream){
  const float* x    = (const float*)d_in[0];
  const int*   ei   = (const int*)d_in[1];
  const int*   batch= (const int*)d_in[2];
  const float* W1   = (const float*)d_in[3];
  const float* as1  = (const float*)d_in[4];
  const float* ad1  = (const float*)d_in[5];
  const float* b1   = (const float*)d_in[6];
  const float* W2   = (const float*)d_in[7];
  const float* as2  = (const float*)d_in[8];
  const float* ad2  = (const float*)d_in[9];
  const float* b2   = (const float*)d_in[10];
  const float* W3   = (const float*)d_in[11];
  const float* as3  = (const float*)d_in[12];
  const float* ad3  = (const float*)d_in[13];
  const float* b3   = (const float*)d_in[14];
  const float* fcw  = (const float*)d_in[15];
  const float* fcb  = (const float*)d_in[16];
  float* out = (float*)d_out;

  const int N = in_sizes[0] / 128;
  const int E = in_sizes[1] / 2;
  const int G = out_size;

  char* p = (char*)d_ws;
  auto alloc = [&](size_t bytes) -> void* {
    void* r = (void*)p;
    p += (bytes + 255) & ~(size_t)255;
    return r;
  };
  float* bufA   = (float*)alloc((size_t)N*128*sizeof(float));
  float* bufB   = (float*)alloc((size_t)N*128*sizeof(float));
  float* asrc   = (float*)alloc((size_t)N*4*sizeof(float));
  float* adst   = (float*)alloc((size_t)N*4*sizeof(float));
  int*   deg    = (int*)alloc((size_t)N*sizeof(int));
  int*   offsets= (int*)alloc((size_t)(N+1)*sizeof(int));
  int*   cursor = (int*)alloc((size_t)N*sizeof(int));
  int*   csr    = (int*)alloc((size_t)E*sizeof(int));
  int*   csums  = (int*)alloc(1024*sizeof(int));
  int*   gstart = (int*)alloc((size_t)(G+1)*sizeof(int));

  const int nchunks = (N + 1023)/1024;

  hipMemsetAsync(deg, 0, (size_t)N*sizeof(int), stream);

  k_degree<<<(E+255)/256, 256, 0, stream>>>(ei, E, deg);
  k_chunk_sum<<<nchunks, 256, 0, stream>>>(deg, N, csums);
  k_scan_chunks<<<1, 1, 0, stream>>>(csums, nchunks, offsets + N);
  k_scan_within<<<nchunks, 256, 0, stream>>>(deg, csums, N, offsets, cursor);
  k_scatter<<<(E+255)/256, 256, 0, stream>>>(ei, E, cursor, csr);
  k_bounds<<<(N+255)/256, 256, 0, stream>>>(batch, N, G, gstart);

  dim3 g12((N+63)/64, 2);
  // layer 1
  k_gemm<<<g12, 256, 0, stream>>>(x, W1, bufB, N, 128);
  k_attn<<<(N*4+255)/256, 256, 0, stream>>>(bufB, as1, ad1, asrc, adst, N, 4, 128);
  k_agg<128><<<((size_t)N*64+255)/256, 256, 0, stream>>>(bufB, asrc, adst, offsets, csr, b1, bufA, N);
  // layer 2
  k_gemm<<<g12, 256, 0, stream>>>(bufA, W2, bufB, N, 128);
  k_attn<<<(N*4+255)/256, 256, 0, stream>>>(bufB, as2, ad2, asrc, adst, N, 4, 128);
  k_agg<128><<<((size_t)N*64+255)/256, 256, 0, stream>>>(bufB, asrc, adst, offsets, csr, b2, bufA, N);
  // layer 3
  dim3 g3((N+63)/64, 1);
  k_gemm<<<g3, 256, 0, stream>>>(bufA, W3, bufB, N, 32);
  k_attn<<<(N+255)/256, 256, 0, stream>>>(bufB, as3, ad3, asrc, adst, N, 1, 32);
  long long waves3 = (N + 1)/2;
  k_agg<32><<<(int)((waves3*64 + 255)/256), 256, 0, stream>>>(bufB, asrc, adst, offsets, csr, b3, bufA, N);
  // readout
  k_pool2<<<G, 256, 0, stream>>>(bufA, gstart, fcw, fcb, out, G);
}

// Round 3
// 990.562 us; speedup vs baseline: 1.3613x; 1.0968x over previous
//
#include <hip/hip_runtime.h>
#include <hip/hip_bf16.h>
#include <math.h>

#define NEG_SLOPE 0.2f

__device__ __forceinline__ float leaky(float x){ return x > 0.f ? x : NEG_SLOPE*x; }
__device__ __forceinline__ float elu(float x){ return x > 0.f ? x : expm1f(x); }

// bf16 (stored as ushort) helpers
__device__ __forceinline__ ushort f2bf(float f){
  uint u = __float_as_uint(f);
  u += 0x7fffu + ((u >> 16) & 1u);            // RNE
  return (ushort)(u >> 16);
}
__device__ __forceinline__ float2 bfpair(uint v){   // uint = two packed bf16 (lo = even ch)
  return make_float2(__uint_as_float(v << 16), __uint_as_float(v & 0xffff0000u));
}

// ---------- CSR build ----------
__global__ __launch_bounds__(256) void k_degree(const int* __restrict__ ei, int E, int* __restrict__ deg){
  int e = blockIdx.x*256 + threadIdx.x;
  if (e >= E) return;
  atomicAdd(&deg[ei[E + e]], 1);
}

__global__ __launch_bounds__(256) void k_chunk_sum(const int* __restrict__ deg, int n, int* __restrict__ cs){
  __shared__ int s[256];
  int base = blockIdx.x*1024;
  int sum = 0;
  for (int i = threadIdx.x; i < 1024; i += 256){
    int idx = base + i;
    if (idx < n) sum += deg[idx];
  }
  s[threadIdx.x] = sum; __syncthreads();
  for (int st = 128; st > 0; st >>= 1){
    if (threadIdx.x < st) s[threadIdx.x] += s[threadIdx.x + st];
    __syncthreads();
  }
  if (threadIdx.x == 0) cs[blockIdx.x] = s[0];
}

// exclusive scan of cs[0..nchunks) in one block (nchunks <= 1024)
__global__ __launch_bounds__(256) void k_scan_chunks(int* __restrict__ cs, int nchunks, int* __restrict__ total_out){
  __shared__ int s[256];
  int tid = threadIdx.x;
  int v[4]; int local = 0;
  #pragma unroll
  for (int i = 0; i < 4; i++){
    int idx = tid*4 + i;
    v[i] = (idx < nchunks) ? cs[idx] : 0;
    local += v[i];
  }
  s[tid] = local; __syncthreads();
  for (int st = 1; st < 256; st <<= 1){
    int val = (tid >= st) ? s[tid - st] : 0;
    __syncthreads();
    s[tid] += val;
    __syncthreads();
  }
  int run = (tid ? s[tid-1] : 0);
  #pragma unroll
  for (int i = 0; i < 4; i++){
    int idx = tid*4 + i;
    if (idx < nchunks){ cs[idx] = run; run += v[i]; }
  }
  if (tid == 255) *total_out = s[255];
}

__global__ __launch_bounds__(256) void k_scan_within(const int* __restrict__ deg, const int* __restrict__ cs,
                              int n, int* __restrict__ offsets, int* __restrict__ cursor){
  __shared__ int s[256];
  int tid = threadIdx.x;
  int base = blockIdx.x*1024;
  int v[4]; int local = 0;
  #pragma unroll
  for (int i = 0; i < 4; i++){
    int idx = base + tid*4 + i;
    v[i] = (idx < n) ? deg[idx] : 0;
    local += v[i];
  }
  s[tid] = local; __syncthreads();
  for (int st = 1; st < 256; st <<= 1){
    int val = (tid >= st) ? s[tid - st] : 0;
    __syncthreads();
    s[tid] += val;
    __syncthreads();
  }
  int run = (tid ? s[tid-1] : 0) + cs[blockIdx.x];
  #pragma unroll
  for (int i = 0; i < 4; i++){
    int idx = base + tid*4 + i;
    if (idx < n){ offsets[idx] = run; cursor[idx] = run; run += v[i]; }
  }
}

__global__ __launch_bounds__(256) void k_scatter(const int* __restrict__ ei, int E,
                          int* __restrict__ cursor, int* __restrict__ csr_src){
  int e = blockIdx.x*256 + threadIdx.x;
  if (e >= E) return;
  int s = ei[e], d = ei[E + e];
  int pos = atomicAdd(&cursor[d], 1);
  csr_src[pos] = s;
}

// ---------- GEMM: Y[n,M](bf16) = X[n,128](f32) @ W[128,M](f32) ----------
__global__ __launch_bounds__(256) void k_gemm(const float* __restrict__ X, const float* __restrict__ W,
                     ushort* __restrict__ Y, int n, int M){
  __shared__ float xs[128][65];           // [k][r], +1 pad: conflict-free
  int rowBase = blockIdx.x*64;
  int cBase = blockIdx.y*64;
  int tid = threadIdx.x;
  for (int idx = tid; idx < 64*128; idx += 256){
    int r = idx >> 7, k = idx & 127;
    int row = rowBase + r;
    xs[k][r] = (row < n) ? X[(size_t)row*128 + k] : 0.f;
  }
  __syncthreads();
  int tr = tid >> 4, tc = tid & 15;
  int r0 = tr*4;
  int c0 = cBase + tc*4;
  float acc[4][4] = {};
  if (c0 < M){
    for (int k = 0; k < 128; k++){
      float4 wv = *(const float4*)(W + (size_t)k*M + c0);
      float x0 = xs[k][r0+0], x1 = xs[k][r0+1], x2 = xs[k][r0+2], x3 = xs[k][r0+3];
      acc[0][0] += x0*wv.x; acc[0][1] += x0*wv.y; acc[0][2] += x0*wv.z; acc[0][3] += x0*wv.w;
      acc[1][0] += x1*wv.x; acc[1][1] += x1*wv.y; acc[1][2] += x1*wv.z; acc[1][3] += x1*wv.w;
      acc[2][0] += x2*wv.x; acc[2][1] += x2*wv.y; acc[2][2] += x2*wv.z; acc[2][3] += x2*wv.w;
      acc[3][0] += x3*wv.x; acc[3][1] += x3*wv.y; acc[3][2] += x3*wv.z; acc[3][3] += x3*wv.w;
    }
    #pragma unroll
    for (int i = 0; i < 4; i++){
      int row = rowBase + r0 + i;
      if (row < n){
        ushort4 o;
        o.x = f2bf(acc[i][0]); o.y = f2bf(acc[i][1]); o.z = f2bf(acc[i][2]); o.w = f2bf(acc[i][3]);
        *(ushort4*)(Y + (size_t)row*M + c0) = o;
      }
    }
  }
}

// ---------- attention coefficients (reads bf16 h) ----------
__global__ __launch_bounds__(256) void k_attn(const ushort* __restrict__ Hb, const float* __restrict__ a_s,
                     const float* __restrict__ a_d, float* __restrict__ asrc, float* __restrict__ adst,
                     int n, int H, int M){
  int idx = blockIdx.x*256 + threadIdx.x;
  if (idx >= n*H) return;
  int node = idx / H, h = idx - node*H;
  const uint4* r4 = (const uint4*)(Hb + (size_t)node*M + h*32);   // 32 bf16 = 64 B, 16B aligned
  const float* as = a_s + h*32;
  const float* ad = a_d + h*32;
  float s1 = 0.f, s2 = 0.f;
  #pragma unroll
  for (int i = 0; i < 4; i++){
    uint4 q = r4[i];
    uint w[4] = {q.x, q.y, q.z, q.w};
    #pragma unroll
    for (int j = 0; j < 4; j++){
      float2 f = bfpair(w[j]);
      int c = i*8 + j*2;
      s1 += f.x*as[c] + f.y*as[c+1];
      s2 += f.x*ad[c] + f.y*ad[c+1];
    }
  }
  asrc[idx] = s1; adst[idx] = s2;
}

// ---------- per-dst softmax-weighted aggregation + bias + ELU ----------
// Pair-channel mapping: each lane owns one uint (2 consecutive bf16 channels, same head).
// HC=128: 1 node/wave (64 uints/row). HC=32: 4 nodes/wave (16 uints/row).
template<int HC>
__global__ __launch_bounds__(256) void k_agg(const ushort* __restrict__ Hb, const float* __restrict__ asrc,
                    const float* __restrict__ adst, const int* __restrict__ offsets,
                    const int* __restrict__ csr_src, const float* __restrict__ bias,
                    float* __restrict__ Out, int n){
  constexpr int H = HC/32;
  constexpr int PAIRS = HC/2;
  int gid = blockIdx.x*256 + threadIdx.x;
  int wave = gid >> 6;
  int lane = threadIdx.x & 63;
  int node, up;
  if (HC == 128){ node = wave;                 up = lane;      }
  else          { node = wave*4 + (lane >> 4); up = lane & 15; }
  if (node >= n) return;
  const int ch = up*2;
  const int h0 = ch >> 5;
  const uint* rows = (const uint*)Hb;
  float ad = adst[node*H + h0];
  float acc0 = 0.f, acc1 = 0.f, den = 0.f;
  // self loop (GATConv adds one per node)
  {
    float w = __expf(leaky(asrc[node*H + h0] + ad));
    float2 f = bfpair(rows[(size_t)node*PAIRS + up]);
    den += w; acc0 += w*f.x; acc1 += w*f.y;
  }
  int j = offsets[node], end = offsets[node+1];
  for (; j < end; j++){
    int s = csr_src[j];
    float w = __expf(leaky(asrc[s*H + h0] + ad));
    float2 f = bfpair(rows[(size_t)s*PAIRS + up]);
    den += w; acc0 += w*f.x; acc1 += w*f.y;
  }
  float inv = 1.f/(den + 1e-16f);
  float2 o;
  o.x = elu(acc0*inv + bias[ch]);
  o.y = elu(acc1*inv + bias[ch+1]);
  *(float2*)(Out + (size_t)node*HC + ch) = o;
}

// ---------- readout: graph boundaries from sorted batch, then pool+fc fused ----------
__global__ __launch_bounds__(256) void k_bounds(const int* __restrict__ batch, int n, int G,
                                                int* __restrict__ gstart){
  int i = blockIdx.x*256 + threadIdx.x;
  if (i >= n) return;
  int b = batch[i];
  int bp = (i > 0) ? batch[i-1] : -1;
  for (int g = bp + 1; g <= b; g++) gstart[g] = i;     // first node of graph g
  if (i == n-1){
    for (int g = b + 1; g <= G; g++) gstart[g] = n;    // tail (incl. gstart[G]=N)
  }
}

__global__ __launch_bounds__(256) void k_pool2(const float* __restrict__ H3,
                     const int* __restrict__ gstart, const float* __restrict__ fcw,
                     const float* __restrict__ fcb, float* __restrict__ out, int G){
  int g = blockIdx.x;
  int s0 = gstart[g], s1 = gstart[g+1];
  int tid = threadIdx.x;
  int c = tid & 31, r = tid >> 5;                      // 8 row-lanes x 32 channels
  float sum = 0.f;
  for (int i = s0 + r; i < s1; i += 8)
    sum += H3[(size_t)i*32 + c];
  __shared__ float sh[8][32];
  sh[r][c] = sum;
  __syncthreads();
  if (tid < 32){
    float t = 0.f;
    #pragma unroll
    for (int k = 0; k < 8; k++) t += sh[k][tid];
    t *= fcw[tid];
    #pragma unroll
    for (int off = 16; off; off >>= 1) t += __shfl_down(t, off, 32);
    if (tid == 0){
      float cnt = (float)(s1 - s0); if (cnt < 1.f) cnt = 1.f;
      out[g] = t/cnt + fcb[0];
    }
  }
}

extern "C" void kernel_launch(void* const* d_in, const int* in_sizes, int n_in,
                              void* d_out, int out_size, void* d_ws, size_t ws_size,
                              hipStream_t stream){
  const float* x    = (const float*)d_in[0];
  const int*   ei   = (const int*)d_in[1];
  const int*   batch= (const int*)d_in[2];
  const float* W1   = (const float*)d_in[3];
  const float* as1  = (const float*)d_in[4];
  const float* ad1  = (const float*)d_in[5];
  const float* b1   = (const float*)d_in[6];
  const float* W2   = (const float*)d_in[7];
  const float* as2  = (const float*)d_in[8];
  const float* ad2  = (const float*)d_in[9];
  const float* b2   = (const float*)d_in[10];
  const float* W3   = (const float*)d_in[11];
  const float* as3  = (const float*)d_in[12];
  const float* ad3  = (const float*)d_in[13];
  const float* b3   = (const float*)d_in[14];
  const float* fcw  = (const float*)d_in[15];
  const float* fcb  = (const float*)d_in[16];
  float* out = (float*)d_out;

  const int N = in_sizes[0] / 128;
  const int E = in_sizes[1] / 2;
  const int G = out_size;

  char* p = (char*)d_ws;
  auto alloc = [&](size_t bytes) -> void* {
    void* r = (void*)p;
    p += (bytes + 255) & ~(size_t)255;
    return r;
  };
  float*  bufA   = (float*)alloc((size_t)N*128*sizeof(float));    // agg output (fp32)
  ushort* bufH   = (ushort*)alloc((size_t)N*128*sizeof(ushort));  // gemm output (bf16)
  float*  asrc   = (float*)alloc((size_t)N*4*sizeof(float));
  float*  adst   = (float*)alloc((size_t)N*4*sizeof(float));
  int*    deg    = (int*)alloc((size_t)N*sizeof(int));
  int*    offsets= (int*)alloc((size_t)(N+1)*sizeof(int));
  int*    cursor = (int*)alloc((size_t)N*sizeof(int));
  int*    csr    = (int*)alloc((size_t)E*sizeof(int));
  int*    csums  = (int*)alloc(1024*sizeof(int));
  int*    gstart = (int*)alloc((size_t)(G+1)*sizeof(int));

  const int nchunks = (N + 1023)/1024;

  hipMemsetAsync(deg, 0, (size_t)N*sizeof(int), stream);

  k_degree<<<(E+255)/256, 256, 0, stream>>>(ei, E, deg);
  k_chunk_sum<<<nchunks, 256, 0, stream>>>(deg, N, csums);
  k_scan_chunks<<<1, 256, 0, stream>>>(csums, nchunks, offsets + N);
  k_scan_within<<<nchunks, 256, 0, stream>>>(deg, csums, N, offsets, cursor);
  k_scatter<<<(E+255)/256, 256, 0, stream>>>(ei, E, cursor, csr);
  k_bounds<<<(N+255)/256, 256, 0, stream>>>(batch, N, G, gstart);

  dim3 g12((N+63)/64, 2);
  // layer 1
  k_gemm<<<g12, 256, 0, stream>>>(x, W1, bufH, N, 128);
  k_attn<<<(N*4+255)/256, 256, 0, stream>>>(bufH, as1, ad1, asrc, adst, N, 4, 128);
  k_agg<128><<<(N*64+255)/256 + (((size_t)N*64)%256 ? 0:0), 256, 0, stream>>>(bufH, asrc, adst, offsets, csr, b1, bufA, N);
  // layer 2
  k_gemm<<<g12, 256, 0, stream>>>(bufA, W2, bufH, N, 128);
  k_attn<<<(N*4+255)/256, 256, 0, stream>>>(bufH, as2, ad2, asrc, adst, N, 4, 128);
  k_agg<128><<<(N*64+255)/256, 256, 0, stream>>>(bufH, asrc, adst, offsets, csr, b2, bufA, N);
  // layer 3
  dim3 g3((N+63)/64, 1);
  k_gemm<<<g3, 256, 0, stream>>>(bufA, W3, bufH, N, 32);
  k_attn<<<(N+255)/256, 256, 0, stream>>>(bufH, as3, ad3, asrc, adst, N, 1, 32);
  int waves3 = (N + 3)/4;                       // 4 nodes per wave
  k_agg<32><<<(waves3*64 + 255)/256, 256, 0, stream>>>(bufH, asrc, adst, offsets, csr, b3, bufA, N);
  // readout
  k_pool2<<<G, 256, 0, stream>>>(bufA, gstart, fcw, fcb, out, G);
}

// Round 4
// 799.233 us; speedup vs baseline: 1.6872x; 1.2394x over previous
//
#include <hip/hip_runtime.h>
#include <hip/hip_bf16.h>
#include <math.h>

#define NEG_SLOPE 0.2f

__device__ __forceinline__ float leaky(float x){ return x > 0.f ? x : NEG_SLOPE*x; }
__device__ __forceinline__ float elu(float x){ return x > 0.f ? x : expm1f(x); }

// bf16 (stored as ushort) helpers
__device__ __forceinline__ ushort f2bf(float f){
  uint u = __float_as_uint(f);
  u += 0x7fffu + ((u >> 16) & 1u);            // RNE
  return (ushort)(u >> 16);
}
__device__ __forceinline__ float2 bfpair(uint v){   // uint = two packed bf16 (lo = even ch)
  return make_float2(__uint_as_float(v << 16), __uint_as_float(v & 0xffff0000u));
}

// ---------- CSR build ----------
__global__ __launch_bounds__(256) void k_degree(const int* __restrict__ ei, int E, int* __restrict__ deg){
  int e = blockIdx.x*256 + threadIdx.x;
  if (e >= E) return;
  atomicAdd(&deg[ei[E + e]], 1);
}

__global__ __launch_bounds__(256) void k_chunk_sum(const int* __restrict__ deg, int n, int* __restrict__ cs){
  __shared__ int s[256];
  int base = blockIdx.x*1024;
  int sum = 0;
  for (int i = threadIdx.x; i < 1024; i += 256){
    int idx = base + i;
    if (idx < n) sum += deg[idx];
  }
  s[threadIdx.x] = sum; __syncthreads();
  for (int st = 128; st > 0; st >>= 1){
    if (threadIdx.x < st) s[threadIdx.x] += s[threadIdx.x + st];
    __syncthreads();
  }
  if (threadIdx.x == 0) cs[blockIdx.x] = s[0];
}

// exclusive scan of cs[0..nchunks) in one block (nchunks <= 1024)
__global__ __launch_bounds__(256) void k_scan_chunks(int* __restrict__ cs, int nchunks, int* __restrict__ total_out){
  __shared__ int s[256];
  int tid = threadIdx.x;
  int v[4]; int local = 0;
  #pragma unroll
  for (int i = 0; i < 4; i++){
    int idx = tid*4 + i;
    v[i] = (idx < nchunks) ? cs[idx] : 0;
    local += v[i];
  }
  s[tid] = local; __syncthreads();
  for (int st = 1; st < 256; st <<= 1){
    int val = (tid >= st) ? s[tid - st] : 0;
    __syncthreads();
    s[tid] += val;
    __syncthreads();
  }
  int run = (tid ? s[tid-1] : 0);
  #pragma unroll
  for (int i = 0; i < 4; i++){
    int idx = tid*4 + i;
    if (idx < nchunks){ cs[idx] = run; run += v[i]; }
  }
  if (tid == 255) *total_out = s[255];
}

__global__ __launch_bounds__(256) void k_scan_within(const int* __restrict__ deg, const int* __restrict__ cs,
                              int n, int* __restrict__ offsets, int* __restrict__ cursor){
  __shared__ int s[256];
  int tid = threadIdx.x;
  int base = blockIdx.x*1024;
  int v[4]; int local = 0;
  #pragma unroll
  for (int i = 0; i < 4; i++){
    int idx = base + tid*4 + i;
    v[i] = (idx < n) ? deg[idx] : 0;
    local += v[i];
  }
  s[tid] = local; __syncthreads();
  for (int st = 1; st < 256; st <<= 1){
    int val = (tid >= st) ? s[tid - st] : 0;
    __syncthreads();
    s[tid] += val;
    __syncthreads();
  }
  int run = (tid ? s[tid-1] : 0) + cs[blockIdx.x];
  #pragma unroll
  for (int i = 0; i < 4; i++){
    int idx = base + tid*4 + i;
    if (idx < n){ offsets[idx] = run; cursor[idx] = run; run += v[i]; }
  }
}

__global__ __launch_bounds__(256) void k_scatter(const int* __restrict__ ei, int E,
                          int* __restrict__ cursor, int* __restrict__ csr_src){
  int e = blockIdx.x*256 + threadIdx.x;
  if (e >= E) return;
  int s = ei[e], d = ei[E + e];
  int pos = atomicAdd(&cursor[d], 1);
  csr_src[pos] = s;
}

// ---------- GEMM: Y[n,M](bf16) = X[n,128](f32) @ W[128,M](f32) ----------
__global__ __launch_bounds__(256) void k_gemm(const float* __restrict__ X, const float* __restrict__ W,
                     ushort* __restrict__ Y, int n, int M){
  __shared__ float xs[128][65];           // [k][r], +1 pad: conflict-free
  int rowBase = blockIdx.x*64;
  int cBase = blockIdx.y*64;
  int tid = threadIdx.x;
  for (int idx = tid; idx < 64*128; idx += 256){
    int r = idx >> 7, k = idx & 127;
    int row = rowBase + r;
    xs[k][r] = (row < n) ? X[(size_t)row*128 + k] : 0.f;
  }
  __syncthreads();
  int tr = tid >> 4, tc = tid & 15;
  int r0 = tr*4;
  int c0 = cBase + tc*4;
  float acc[4][4] = {};
  if (c0 < M){
    for (int k = 0; k < 128; k++){
      float4 wv = *(const float4*)(W + (size_t)k*M + c0);
      float x0 = xs[k][r0+0], x1 = xs[k][r0+1], x2 = xs[k][r0+2], x3 = xs[k][r0+3];
      acc[0][0] += x0*wv.x; acc[0][1] += x0*wv.y; acc[0][2] += x0*wv.z; acc[0][3] += x0*wv.w;
      acc[1][0] += x1*wv.x; acc[1][1] += x1*wv.y; acc[1][2] += x1*wv.z; acc[1][3] += x1*wv.w;
      acc[2][0] += x2*wv.x; acc[2][1] += x2*wv.y; acc[2][2] += x2*wv.z; acc[2][3] += x2*wv.w;
      acc[3][0] += x3*wv.x; acc[3][1] += x3*wv.y; acc[3][2] += x3*wv.z; acc[3][3] += x3*wv.w;
    }
    #pragma unroll
    for (int i = 0; i < 4; i++){
      int row = rowBase + r0 + i;
      if (row < n){
        ushort4 o;
        o.x = f2bf(acc[i][0]); o.y = f2bf(acc[i][1]); o.z = f2bf(acc[i][2]); o.w = f2bf(acc[i][3]);
        *(ushort4*)(Y + (size_t)row*M + c0) = o;
      }
    }
  }
}

// ---------- attention coefficients (reads bf16 h) ----------
__global__ __launch_bounds__(256) void k_attn(const ushort* __restrict__ Hb, const float* __restrict__ a_s,
                     const float* __restrict__ a_d, float* __restrict__ asrc, float* __restrict__ adst,
                     int n, int H, int M){
  int idx = blockIdx.x*256 + threadIdx.x;
  if (idx >= n*H) return;
  int node = idx / H, h = idx - node*H;
  const uint4* r4 = (const uint4*)(Hb + (size_t)node*M + h*32);   // 32 bf16 = 64 B, 16B aligned
  const float* as = a_s + h*32;
  const float* ad = a_d + h*32;
  float s1 = 0.f, s2 = 0.f;
  #pragma unroll
  for (int i = 0; i < 4; i++){
    uint4 q = r4[i];
    uint w[4] = {q.x, q.y, q.z, q.w};
    #pragma unroll
    for (int j = 0; j < 4; j++){
      float2 f = bfpair(w[j]);
      int c = i*8 + j*2;
      s1 += f.x*as[c] + f.y*as[c+1];
      s2 += f.x*ad[c] + f.y*ad[c+1];
    }
  }
  asrc[idx] = s1; adst[idx] = s2;
}

// ---------- per-dst softmax-weighted aggregation + bias + ELU ----------
// Pair-channel mapping: each lane owns one uint (2 consecutive bf16 channels, same head).
// HC=128: 1 node/wave (64 uints/row); src index is wave-uniform -> readfirstlane/SGPR addressing.
// HC=32: 4 nodes/wave (16 uints/row); index uniform only per 16-lane group -> vector addressing.
// 4-way software pipeline: 4 independent csr-index loads, then 4 independent asrc+row loads.
template<int HC>
__global__ __launch_bounds__(256) void k_agg(const ushort* __restrict__ Hb, const float* __restrict__ asrc,
                    const float* __restrict__ adst, const int* __restrict__ offsets,
                    const int* __restrict__ csr_src, const float* __restrict__ bias,
                    float* __restrict__ Out, int n){
  constexpr int H = HC/32;
  constexpr int PAIRS = HC/2;
  int gid = blockIdx.x*256 + threadIdx.x;
  int wave = gid >> 6;
  int lane = threadIdx.x & 63;
  int node, up;
  if (HC == 128){ node = wave;                 up = lane;      }
  else          { node = wave*4 + (lane >> 4); up = lane & 15; }
  if (node >= n) return;
  const int ch = up*2;
  const int h0 = ch >> 5;
  const uint* rows = (const uint*)Hb;
  float ad = adst[node*H + h0];
  float acc0 = 0.f, acc1 = 0.f, den = 0.f;
  // self loop (GATConv adds one per node)
  {
    float w = __expf(leaky(asrc[node*H + h0] + ad));
    float2 f = bfpair(rows[(size_t)node*PAIRS + up]);
    den += w; acc0 += w*f.x; acc1 += w*f.y;
  }
  int j = offsets[node], end = offsets[node+1];
  // ---- 4-way pipelined main loop ----
  for (; j + 4 <= end; j += 4){
    int s0 = csr_src[j], s1 = csr_src[j+1], s2 = csr_src[j+2], s3 = csr_src[j+3];
    if (HC == 128){                       // wave-uniform: move to SGPRs, scalar addr math
      s0 = __builtin_amdgcn_readfirstlane(s0);
      s1 = __builtin_amdgcn_readfirstlane(s1);
      s2 = __builtin_amdgcn_readfirstlane(s2);
      s3 = __builtin_amdgcn_readfirstlane(s3);
    }
    float e0 = asrc[s0*H + h0], e1 = asrc[s1*H + h0], e2 = asrc[s2*H + h0], e3 = asrc[s3*H + h0];
    uint r0 = rows[(size_t)s0*PAIRS + up];
    uint r1 = rows[(size_t)s1*PAIRS + up];
    uint r2 = rows[(size_t)s2*PAIRS + up];
    uint r3 = rows[(size_t)s3*PAIRS + up];
    float w0 = __expf(leaky(e0 + ad));
    float w1 = __expf(leaky(e1 + ad));
    float w2 = __expf(leaky(e2 + ad));
    float w3 = __expf(leaky(e3 + ad));
    float2 f0 = bfpair(r0), f1 = bfpair(r1), f2 = bfpair(r2), f3 = bfpair(r3);
    den  += (w0 + w1) + (w2 + w3);
    acc0 += w0*f0.x + w1*f1.x + w2*f2.x + w3*f3.x;
    acc1 += w0*f0.y + w1*f1.y + w2*f2.y + w3*f3.y;
  }
  // ---- remainder ----
  for (; j < end; j++){
    int s = csr_src[j];
    if (HC == 128) s = __builtin_amdgcn_readfirstlane(s);
    float w = __expf(leaky(asrc[s*H + h0] + ad));
    float2 f = bfpair(rows[(size_t)s*PAIRS + up]);
    den += w; acc0 += w*f.x; acc1 += w*f.y;
  }
  float inv = 1.f/(den + 1e-16f);
  float2 o;
  o.x = elu(acc0*inv + bias[ch]);
  o.y = elu(acc1*inv + bias[ch+1]);
  *(float2*)(Out + (size_t)node*HC + ch) = o;
}

// ---------- readout: graph boundaries from sorted batch, then pool+fc fused ----------
__global__ __launch_bounds__(256) void k_bounds(const int* __restrict__ batch, int n, int G,
                                                int* __restrict__ gstart){
  int i = blockIdx.x*256 + threadIdx.x;
  if (i >= n) return;
  int b = batch[i];
  int bp = (i > 0) ? batch[i-1] : -1;
  for (int g = bp + 1; g <= b; g++) gstart[g] = i;     // first node of graph g
  if (i == n-1){
    for (int g = b + 1; g <= G; g++) gstart[g] = n;    // tail (incl. gstart[G]=N)
  }
}

__global__ __launch_bounds__(256) void k_pool2(const float* __restrict__ H3,
                     const int* __restrict__ gstart, const float* __restrict__ fcw,
                     const float* __restrict__ fcb, float* __restrict__ out, int G){
  int g = blockIdx.x;
  int s0 = gstart[g], s1 = gstart[g+1];
  int tid = threadIdx.x;
  int c = tid & 31, r = tid >> 5;                      // 8 row-lanes x 32 channels
  float sum = 0.f;
  for (int i = s0 + r; i < s1; i += 8)
    sum += H3[(size_t)i*32 + c];
  __shared__ float sh[8][32];
  sh[r][c] = sum;
  __syncthreads();
  if (tid < 32){
    float t = 0.f;
    #pragma unroll
    for (int k = 0; k < 8; k++) t += sh[k][tid];
    t *= fcw[tid];
    #pragma unroll
    for (int off = 16; off; off >>= 1) t += __shfl_down(t, off, 32);
    if (tid == 0){
      float cnt = (float)(s1 - s0); if (cnt < 1.f) cnt = 1.f;
      out[g] = t/cnt + fcb[0];
    }
  }
}

extern "C" void kernel_launch(void* const* d_in, const int* in_sizes, int n_in,
                              void* d_out, int out_size, void* d_ws, size_t ws_size,
                              hipStream_t stream){
  const float* x    = (const float*)d_in[0];
  const int*   ei   = (const int*)d_in[1];
  const int*   batch= (const int*)d_in[2];
  const float* W1   = (const float*)d_in[3];
  const float* as1  = (const float*)d_in[4];
  const float* ad1  = (const float*)d_in[5];
  const float* b1   = (const float*)d_in[6];
  const float* W2   = (const float*)d_in[7];
  const float* as2  = (const float*)d_in[8];
  const float* ad2  = (const float*)d_in[9];
  const float* b2   = (const float*)d_in[10];
  const float* W3   = (const float*)d_in[11];
  const float* as3  = (const float*)d_in[12];
  const float* ad3  = (const float*)d_in[13];
  const float* b3   = (const float*)d_in[14];
  const float* fcw  = (const float*)d_in[15];
  const float* fcb  = (const float*)d_in[16];
  float* out = (float*)d_out;

  const int N = in_sizes[0] / 128;
  const int E = in_sizes[1] / 2;
  const int G = out_size;

  char* p = (char*)d_ws;
  auto alloc = [&](size_t bytes) -> void* {
    void* r = (void*)p;
    p += (bytes + 255) & ~(size_t)255;
    return r;
  };
  float*  bufA   = (float*)alloc((size_t)N*128*sizeof(float));    // agg output (fp32)
  ushort* bufH   = (ushort*)alloc((size_t)N*128*sizeof(ushort));  // gemm output (bf16)
  float*  asrc   = (float*)alloc((size_t)N*4*sizeof(float));
  float*  adst   = (float*)alloc((size_t)N*4*sizeof(float));
  int*    deg    = (int*)alloc((size_t)N*sizeof(int));
  int*    offsets= (int*)alloc((size_t)(N+1)*sizeof(int));
  int*    cursor = (int*)alloc((size_t)N*sizeof(int));
  int*    csr    = (int*)alloc((size_t)E*sizeof(int));
  int*    csums  = (int*)alloc(1024*sizeof(int));
  int*    gstart = (int*)alloc((size_t)(G+1)*sizeof(int));

  const int nchunks = (N + 1023)/1024;

  hipMemsetAsync(deg, 0, (size_t)N*sizeof(int), stream);

  k_degree<<<(E+255)/256, 256, 0, stream>>>(ei, E, deg);
  k_chunk_sum<<<nchunks, 256, 0, stream>>>(deg, N, csums);
  k_scan_chunks<<<1, 256, 0, stream>>>(csums, nchunks, offsets + N);
  k_scan_within<<<nchunks, 256, 0, stream>>>(deg, csums, N, offsets, cursor);
  k_scatter<<<(E+255)/256, 256, 0, stream>>>(ei, E, cursor, csr);
  k_bounds<<<(N+255)/256, 256, 0, stream>>>(batch, N, G, gstart);

  dim3 g12((N+63)/64, 2);
  // layer 1
  k_gemm<<<g12, 256, 0, stream>>>(x, W1, bufH, N, 128);
  k_attn<<<(N*4+255)/256, 256, 0, stream>>>(bufH, as1, ad1, asrc, adst, N, 4, 128);
  k_agg<128><<<(N*64+255)/256, 256, 0, stream>>>(bufH, asrc, adst, offsets, csr, b1, bufA, N);
  // layer 2
  k_gemm<<<g12, 256, 0, stream>>>(bufA, W2, bufH, N, 128);
  k_attn<<<(N*4+255)/256, 256, 0, stream>>>(bufH, as2, ad2, asrc, adst, N, 4, 128);
  k_agg<128><<<(N*64+255)/256, 256, 0, stream>>>(bufH, asrc, adst, offsets, csr, b2, bufA, N);
  // layer 3
  dim3 g3((N+63)/64, 1);
  k_gemm<<<g3, 256, 0, stream>>>(bufA, W3, bufH, N, 32);
  k_attn<<<(N+255)/256, 256, 0, stream>>>(bufH, as3, ad3, asrc, adst, N, 1, 32);
  int waves3 = (N + 3)/4;                       // 4 nodes per wave
  k_agg<32><<<(waves3*64 + 255)/256, 256, 0, stream>>>(bufH, asrc, adst, offsets, csr, b3, bufA, N);
  // readout
  k_pool2<<<G, 256, 0, stream>>>(bufA, gstart, fcw, fcb, out, G);
}

// Round 5
// 674.672 us; speedup vs baseline: 1.9987x; 1.1846x over previous
//
#include <hip/hip_runtime.h>
#include <hip/hip_bf16.h>
#include <math.h>

#define NEG_SLOPE 0.2f
#define CHUNK 6144         // edges staged per block in k_scatA (LDS budget ~57 KB)

__device__ __forceinline__ float leaky(float x){ return x > 0.f ? x : NEG_SLOPE*x; }
__device__ __forceinline__ float elu(float x){ return x > 0.f ? x : expm1f(x); }

// bf16 (stored as ushort) helpers
__device__ __forceinline__ ushort f2bf(float f){
  uint u = __float_as_uint(f);
  u += 0x7fffu + ((u >> 16) & 1u);            // RNE
  return (ushort)(u >> 16);
}
__device__ __forceinline__ float2 bfpair(uint v){   // uint = two packed bf16 (lo = even ch)
  return make_float2(__uint_as_float(v << 16), __uint_as_float(v & 0xffff0000u));
}

// ---------- CSR build: two-level bucketed counting sort ----------
// bucket = dst >> 8 (256 nodes/bucket). Packed edge: (src<<8)|(dst&255), valid for src < 2^24.

__global__ __launch_bounds__(256) void k_histA(const int* __restrict__ ei, int E,
                                               int* __restrict__ bucketCount){
  __shared__ int hist[512];
  for (int b = threadIdx.x; b < 512; b += 256) hist[b] = 0;
  __syncthreads();
  int base = blockIdx.x * 2048;
  int cnt = min(2048, E - base);
  for (int i = threadIdx.x; i < cnt; i += 256)
    atomicAdd(&hist[ei[E + base + i] >> 8], 1);
  __syncthreads();
  for (int b = threadIdx.x; b < 512; b += 256)
    if (hist[b]) atomicAdd(&bucketCount[b], hist[b]);
}

__global__ __launch_bounds__(256) void k_scanB(const int* __restrict__ bucketCount, int NB,
                        int* __restrict__ bucketBase, int* __restrict__ gcursor, int E){
  __shared__ int s[512];
  for (int b = threadIdx.x; b < 512; b += 256)
    s[b] = (b < NB) ? bucketCount[b] : 0;
  __syncthreads();
  if (threadIdx.x == 0){
    int run = 0;
    for (int b = 0; b < NB; b++){ int v = s[b]; s[b] = run; run += v; }
  }
  __syncthreads();
  for (int b = threadIdx.x; b < NB; b += 256){
    bucketBase[b] = s[b]; gcursor[b] = s[b];
  }
  if (threadIdx.x == 0) bucketBase[NB] = E;
}

__global__ __launch_bounds__(256) void k_scatA(const int* __restrict__ ei, int E, int NB,
                         int* __restrict__ gcursor, uint* __restrict__ tmp){
  __shared__ uint stageS[CHUNK];
  __shared__ uint stageD[CHUNK];
  __shared__ int hist[512], pre[512], cur[512], gbase[512];
  __shared__ int scanArr[256];
  int tid = threadIdx.x;
  int base = blockIdx.x * CHUNK;
  int cnt = min(CHUNK, E - base);
  for (int b = tid; b < 512; b += 256) hist[b] = 0;
  __syncthreads();
  for (int i = tid; i < cnt; i += 256)
    atomicAdd(&hist[ei[E + base + i] >> 8], 1);
  __syncthreads();
  // exclusive scan of hist[0..512) with 2 entries per thread
  int a0 = hist[2*tid], a1 = hist[2*tid+1];
  scanArr[tid] = a0 + a1;
  __syncthreads();
  for (int st = 1; st < 256; st <<= 1){
    int v = (tid >= st) ? scanArr[tid - st] : 0;
    __syncthreads();
    scanArr[tid] += v;
    __syncthreads();
  }
  int eb = tid ? scanArr[tid-1] : 0;
  pre[2*tid] = eb;       cur[2*tid] = eb;
  pre[2*tid+1] = eb + a0; cur[2*tid+1] = eb + a0;
  // reserve contiguous global space per bucket
  if (2*tid < NB && a0 > 0)     gbase[2*tid]   = atomicAdd(&gcursor[2*tid],   a0);
  if (2*tid+1 < NB && a1 > 0)   gbase[2*tid+1] = atomicAdd(&gcursor[2*tid+1], a1);
  __syncthreads();
  // stage edges grouped by bucket
  for (int i = tid; i < cnt; i += 256){
    int s = ei[base + i];
    int d = ei[E + base + i];
    int lpos = atomicAdd(&cur[d >> 8], 1);
    stageS[lpos] = (uint)s; stageD[lpos] = (uint)d;
  }
  __syncthreads();
  // write out bucket-grouped bursts
  for (int i = tid; i < cnt; i += 256){
    uint d = stageD[i];
    int b = d >> 8;
    tmp[gbase[b] + (i - pre[b])] = (stageS[i] << 8) | (d & 255u);
  }
}

__global__ __launch_bounds__(256) void k_csr(const uint* __restrict__ tmp,
                      const int* __restrict__ bucketBase,
                      int N, int NB, int* __restrict__ offsets, int* __restrict__ csr){
  int b = blockIdx.x;
  int nodeBase = b << 8;
  int nNodes = min(256, N - nodeBase);
  int eBeg = bucketBase[b], eEnd = bucketBase[b+1];
  __shared__ int deg[256], cur[256];
  int tid = threadIdx.x;
  deg[tid] = 0;
  __syncthreads();
  for (int e = eBeg + tid; e < eEnd; e += 256)
    atomicAdd(&deg[tmp[e] & 255u], 1);
  __syncthreads();
  cur[tid] = deg[tid];
  __syncthreads();
  for (int st = 1; st < 256; st <<= 1){
    int w = (tid >= st) ? cur[tid - st] : 0;
    __syncthreads();
    cur[tid] += w;
    __syncthreads();
  }
  int excl = tid ? cur[tid-1] : 0;
  __syncthreads();
  cur[tid] = excl;
  if (tid < nNodes) offsets[nodeBase + tid] = eBeg + excl;
  if (b == NB-1 && tid == 0) offsets[N] = eEnd;
  __syncthreads();
  for (int e = eBeg + tid; e < eEnd; e += 256){
    uint u = tmp[e];
    int lpos = atomicAdd(&cur[u & 255u], 1);
    csr[eBeg + lpos] = (int)(u >> 8);
  }
}

// ---------- GEMM: Y[n,M](bf16) = X[n,128](f32) @ W[128,M](f32) ----------
__global__ __launch_bounds__(256) void k_gemm(const float* __restrict__ X, const float* __restrict__ W,
                     ushort* __restrict__ Y, int n, int M){
  __shared__ float xs[128][65];           // [k][r], +1 pad: conflict-free
  int rowBase = blockIdx.x*64;
  int cBase = blockIdx.y*64;
  int tid = threadIdx.x;
  for (int idx = tid; idx < 64*128; idx += 256){
    int r = idx >> 7, k = idx & 127;
    int row = rowBase + r;
    xs[k][r] = (row < n) ? X[(size_t)row*128 + k] : 0.f;
  }
  __syncthreads();
  int tr = tid >> 4, tc = tid & 15;
  int r0 = tr*4;
  int c0 = cBase + tc*4;
  float acc[4][4] = {};
  if (c0 < M){
    for (int k = 0; k < 128; k++){
      float4 wv = *(const float4*)(W + (size_t)k*M + c0);
      float x0 = xs[k][r0+0], x1 = xs[k][r0+1], x2 = xs[k][r0+2], x3 = xs[k][r0+3];
      acc[0][0] += x0*wv.x; acc[0][1] += x0*wv.y; acc[0][2] += x0*wv.z; acc[0][3] += x0*wv.w;
      acc[1][0] += x1*wv.x; acc[1][1] += x1*wv.y; acc[1][2] += x1*wv.z; acc[1][3] += x1*wv.w;
      acc[2][0] += x2*wv.x; acc[2][1] += x2*wv.y; acc[2][2] += x2*wv.z; acc[2][3] += x2*wv.w;
      acc[3][0] += x3*wv.x; acc[3][1] += x3*wv.y; acc[3][2] += x3*wv.z; acc[3][3] += x3*wv.w;
    }
    #pragma unroll
    for (int i = 0; i < 4; i++){
      int row = rowBase + r0 + i;
      if (row < n){
        ushort4 o;
        o.x = f2bf(acc[i][0]); o.y = f2bf(acc[i][1]); o.z = f2bf(acc[i][2]); o.w = f2bf(acc[i][3]);
        *(ushort4*)(Y + (size_t)row*M + c0) = o;
      }
    }
  }
}

// ---------- attention coefficients (reads bf16 h) ----------
__global__ __launch_bounds__(256) void k_attn(const ushort* __restrict__ Hb, const float* __restrict__ a_s,
                     const float* __restrict__ a_d, float* __restrict__ asrc, float* __restrict__ adst,
                     int n, int H, int M){
  int idx = blockIdx.x*256 + threadIdx.x;
  if (idx >= n*H) return;
  int node = idx / H, h = idx - node*H;
  const uint4* r4 = (const uint4*)(Hb + (size_t)node*M + h*32);   // 32 bf16 = 64 B, 16B aligned
  const float* as = a_s + h*32;
  const float* ad = a_d + h*32;
  float s1 = 0.f, s2 = 0.f;
  #pragma unroll
  for (int i = 0; i < 4; i++){
    uint4 q = r4[i];
    uint w[4] = {q.x, q.y, q.z, q.w};
    #pragma unroll
    for (int j = 0; j < 4; j++){
      float2 f = bfpair(w[j]);
      int c = i*8 + j*2;
      s1 += f.x*as[c] + f.y*as[c+1];
      s2 += f.x*ad[c] + f.y*ad[c+1];
    }
  }
  asrc[idx] = s1; adst[idx] = s2;
}

// ---------- per-dst softmax-weighted aggregation + bias + ELU ----------
template<int HC>
__global__ __launch_bounds__(256) void k_agg(const ushort* __restrict__ Hb, const float* __restrict__ asrc,
                    const float* __restrict__ adst, const int* __restrict__ offsets,
                    const int* __restrict__ csr_src, const float* __restrict__ bias,
                    float* __restrict__ Out, int n){
  constexpr int H = HC/32;
  constexpr int PAIRS = HC/2;
  int gid = blockIdx.x*256 + threadIdx.x;
  int wave = gid >> 6;
  int lane = threadIdx.x & 63;
  int node, up;
  if (HC == 128){ node = wave;                 up = lane;      }
  else          { node = wave*4 + (lane >> 4); up = lane & 15; }
  if (node >= n) return;
  const int ch = up*2;
  const int h0 = ch >> 5;
  const uint* rows = (const uint*)Hb;
  float ad = adst[node*H + h0];
  float acc0 = 0.f, acc1 = 0.f, den = 0.f;
  // self loop (GATConv adds one per node)
  {
    float w = __expf(leaky(asrc[node*H + h0] + ad));
    float2 f = bfpair(rows[(size_t)node*PAIRS + up]);
    den += w; acc0 += w*f.x; acc1 += w*f.y;
  }
  int j = offsets[node], end = offsets[node+1];
  // ---- 4-way pipelined main loop ----
  for (; j + 4 <= end; j += 4){
    int s0 = csr_src[j], s1 = csr_src[j+1], s2 = csr_src[j+2], s3 = csr_src[j+3];
    if (HC == 128){                       // wave-uniform: move to SGPRs, scalar addr math
      s0 = __builtin_amdgcn_readfirstlane(s0);
      s1 = __builtin_amdgcn_readfirstlane(s1);
      s2 = __builtin_amdgcn_readfirstlane(s2);
      s3 = __builtin_amdgcn_readfirstlane(s3);
    }
    float e0 = asrc[s0*H + h0], e1 = asrc[s1*H + h0], e2 = asrc[s2*H + h0], e3 = asrc[s3*H + h0];
    uint r0 = rows[(size_t)s0*PAIRS + up];
    uint r1 = rows[(size_t)s1*PAIRS + up];
    uint r2 = rows[(size_t)s2*PAIRS + up];
    uint r3 = rows[(size_t)s3*PAIRS + up];
    float w0 = __expf(leaky(e0 + ad));
    float w1 = __expf(leaky(e1 + ad));
    float w2 = __expf(leaky(e2 + ad));
    float w3 = __expf(leaky(e3 + ad));
    float2 f0 = bfpair(r0), f1 = bfpair(r1), f2 = bfpair(r2), f3 = bfpair(r3);
    den  += (w0 + w1) + (w2 + w3);
    acc0 += w0*f0.x + w1*f1.x + w2*f2.x + w3*f3.x;
    acc1 += w0*f0.y + w1*f1.y + w2*f2.y + w3*f3.y;
  }
  // ---- remainder ----
  for (; j < end; j++){
    int s = csr_src[j];
    if (HC == 128) s = __builtin_amdgcn_readfirstlane(s);
    float w = __expf(leaky(asrc[s*H + h0] + ad));
    float2 f = bfpair(rows[(size_t)s*PAIRS + up]);
    den += w; acc0 += w*f.x; acc1 += w*f.y;
  }
  float inv = 1.f/(den + 1e-16f);
  float2 o;
  o.x = elu(acc0*inv + bias[ch]);
  o.y = elu(acc1*inv + bias[ch+1]);
  *(float2*)(Out + (size_t)node*HC + ch) = o;
}

// ---------- readout: graph boundaries from sorted batch, then pool+fc fused ----------
__global__ __launch_bounds__(256) void k_bounds(const int* __restrict__ batch, int n, int G,
                                                int* __restrict__ gstart){
  int i = blockIdx.x*256 + threadIdx.x;
  if (i >= n) return;
  int b = batch[i];
  int bp = (i > 0) ? batch[i-1] : -1;
  for (int g = bp + 1; g <= b; g++) gstart[g] = i;     // first node of graph g
  if (i == n-1){
    for (int g = b + 1; g <= G; g++) gstart[g] = n;    // tail (incl. gstart[G]=N)
  }
}

__global__ __launch_bounds__(256) void k_pool2(const float* __restrict__ H3,
                     const int* __restrict__ gstart, const float* __restrict__ fcw,
                     const float* __restrict__ fcb, float* __restrict__ out, int G){
  int g = blockIdx.x;
  int s0 = gstart[g], s1 = gstart[g+1];
  int tid = threadIdx.x;
  int c = tid & 31, r = tid >> 5;                      // 8 row-lanes x 32 channels
  float sum = 0.f;
  for (int i = s0 + r; i < s1; i += 8)
    sum += H3[(size_t)i*32 + c];
  __shared__ float sh[8][32];
  sh[r][c] = sum;
  __syncthreads();
  if (tid < 32){
    float t = 0.f;
    #pragma unroll
    for (int k = 0; k < 8; k++) t += sh[k][tid];
    t *= fcw[tid];
    #pragma unroll
    for (int off = 16; off; off >>= 1) t += __shfl_down(t, off, 32);
    if (tid == 0){
      float cnt = (float)(s1 - s0); if (cnt < 1.f) cnt = 1.f;
      out[g] = t/cnt + fcb[0];
    }
  }
}

extern "C" void kernel_launch(void* const* d_in, const int* in_sizes, int n_in,
                              void* d_out, int out_size, void* d_ws, size_t ws_size,
                              hipStream_t stream){
  const float* x    = (const float*)d_in[0];
  const int*   ei   = (const int*)d_in[1];
  const int*   batch= (const int*)d_in[2];
  const float* W1   = (const float*)d_in[3];
  const float* as1  = (const float*)d_in[4];
  const float* ad1  = (const float*)d_in[5];
  const float* b1   = (const float*)d_in[6];
  const float* W2   = (const float*)d_in[7];
  const float* as2  = (const float*)d_in[8];
  const float* ad2  = (const float*)d_in[9];
  const float* b2   = (const float*)d_in[10];
  const float* W3   = (const float*)d_in[11];
  const float* as3  = (const float*)d_in[12];
  const float* ad3  = (const float*)d_in[13];
  const float* b3   = (const float*)d_in[14];
  const float* fcw  = (const float*)d_in[15];
  const float* fcb  = (const float*)d_in[16];
  float* out = (float*)d_out;

  const int N = in_sizes[0] / 128;
  const int E = in_sizes[1] / 2;
  const int G = out_size;
  const int NB = (N + 255) >> 8;           // buckets of 256 nodes

  char* p = (char*)d_ws;
  auto alloc = [&](size_t bytes) -> void* {
    void* r = (void*)p;
    p += (bytes + 255) & ~(size_t)255;
    return r;
  };
  float*  bufA   = (float*)alloc((size_t)N*128*sizeof(float));    // agg output (fp32)
  ushort* bufH   = (ushort*)alloc((size_t)N*128*sizeof(ushort));  // gemm output (bf16)
  float*  asrc   = (float*)alloc((size_t)N*4*sizeof(float));
  float*  adst   = (float*)alloc((size_t)N*4*sizeof(float));
  int*    offsets= (int*)alloc((size_t)(N+1)*sizeof(int));
  int*    csr    = (int*)alloc((size_t)E*sizeof(int));
  uint*   tmp    = (uint*)alloc((size_t)E*sizeof(uint));
  int*    bCount = (int*)alloc(512*sizeof(int));
  int*    bBase  = (int*)alloc(520*sizeof(int));
  int*    gcursor= (int*)alloc(512*sizeof(int));
  int*    gstart = (int*)alloc((size_t)(G+1)*sizeof(int));

  hipMemsetAsync(bCount, 0, 512*sizeof(int), stream);

  k_histA<<<(E+2047)/2048, 256, 0, stream>>>(ei, E, bCount);
  k_scanB<<<1, 256, 0, stream>>>(bCount, NB, bBase, gcursor, E);
  k_scatA<<<(E+CHUNK-1)/CHUNK, 256, 0, stream>>>(ei, E, NB, gcursor, tmp);
  k_csr<<<NB, 256, 0, stream>>>(tmp, bBase, N, NB, offsets, csr);
  k_bounds<<<(N+255)/256, 256, 0, stream>>>(batch, N, G, gstart);

  dim3 g12((N+63)/64, 2);
  // layer 1
  k_gemm<<<g12, 256, 0, stream>>>(x, W1, bufH, N, 128);
  k_attn<<<(N*4+255)/256, 256, 0, stream>>>(bufH, as1, ad1, asrc, adst, N, 4, 128);
  k_agg<128><<<(N*64+255)/256, 256, 0, stream>>>(bufH, asrc, adst, offsets, csr, b1, bufA, N);
  // layer 2
  k_gemm<<<g12, 256, 0, stream>>>(bufA, W2, bufH, N, 128);
  k_attn<<<(N*4+255)/256, 256, 0, stream>>>(bufH, as2, ad2, asrc, adst, N, 4, 128);
  k_agg<128><<<(N*64+255)/256, 256, 0, stream>>>(bufH, asrc, adst, offsets, csr, b2, bufA, N);
  // layer 3
  dim3 g3((N+63)/64, 1);
  k_gemm<<<g3, 256, 0, stream>>>(bufA, W3, bufH, N, 32);
  k_attn<<<(N+255)/256, 256, 0, stream>>>(bufH, as3, ad3, asrc, adst, N, 1, 32);
  int waves3 = (N + 3)/4;                       // 4 nodes per wave
  k_agg<32><<<(waves3*64 + 255)/256, 256, 0, stream>>>(bufH, asrc, adst, offsets, csr, b3, bufA, N);
  // readout
  k_pool2<<<G, 256, 0, stream>>>(bufA, gstart, fcw, fcb, out, G);
}

// Round 6
// 484.883 us; speedup vs baseline: 2.7810x; 1.3914x over previous
//
#include <hip/hip_runtime.h>
#include <hip/hip_bf16.h>
#include <math.h>

#define NEG_SLOPE 0.2f
#define CHUNK 6144         // edges staged per block in k_scatA

typedef short bf16x8 __attribute__((ext_vector_type(8)));
typedef float f32x4  __attribute__((ext_vector_type(4)));

__device__ __forceinline__ float leaky(float x){ return x > 0.f ? x : NEG_SLOPE*x; }
__device__ __forceinline__ float elu(float x){ return x > 0.f ? x : expm1f(x); }

__device__ __forceinline__ ushort f2bf(float f){
  uint u = __float_as_uint(f);
  u += 0x7fffu + ((u >> 16) & 1u);            // RNE
  return (ushort)(u >> 16);
}
__device__ __forceinline__ uint pk2(float lo, float hi){
  return (uint)f2bf(lo) | ((uint)f2bf(hi) << 16);
}
__device__ __forceinline__ float2 bfpair(uint v){   // uint = two packed bf16 (lo = even ch)
  return make_float2(__uint_as_float(v << 16), __uint_as_float(v & 0xffff0000u));
}

// ---------- CSR build: two-level bucketed counting sort ----------
__global__ __launch_bounds__(256) void k_histA(const int* __restrict__ ei, int E,
                                               int* __restrict__ bucketCount){
  __shared__ int hist[512];
  for (int b = threadIdx.x; b < 512; b += 256) hist[b] = 0;
  __syncthreads();
  int base = blockIdx.x * 2048;
  int cnt = min(2048, E - base);
  for (int i = threadIdx.x; i < cnt; i += 256)
    atomicAdd(&hist[ei[E + base + i] >> 8], 1);
  __syncthreads();
  for (int b = threadIdx.x; b < 512; b += 256)
    if (hist[b]) atomicAdd(&bucketCount[b], hist[b]);
}

__global__ __launch_bounds__(256) void k_scanB(const int* __restrict__ bucketCount, int NB,
                        int* __restrict__ bucketBase, int* __restrict__ gcursor, int E){
  __shared__ int s[512];
  for (int b = threadIdx.x; b < 512; b += 256)
    s[b] = (b < NB) ? bucketCount[b] : 0;
  __syncthreads();
  if (threadIdx.x == 0){
    int run = 0;
    for (int b = 0; b < NB; b++){ int v = s[b]; s[b] = run; run += v; }
  }
  __syncthreads();
  for (int b = threadIdx.x; b < NB; b += 256){
    bucketBase[b] = s[b]; gcursor[b] = s[b];
  }
  if (threadIdx.x == 0) bucketBase[NB] = E;
}

__global__ __launch_bounds__(256) void k_scatA(const int* __restrict__ ei, int E, int NB,
                         int* __restrict__ gcursor, uint* __restrict__ tmp){
  __shared__ uint stageS[CHUNK];
  __shared__ uint stageD[CHUNK];
  __shared__ int hist[512], pre[512], cur[512], gbase[512];
  __shared__ int scanArr[256];
  int tid = threadIdx.x;
  int base = blockIdx.x * CHUNK;
  int cnt = min(CHUNK, E - base);
  for (int b = tid; b < 512; b += 256) hist[b] = 0;
  __syncthreads();
  for (int i = tid; i < cnt; i += 256)
    atomicAdd(&hist[ei[E + base + i] >> 8], 1);
  __syncthreads();
  int a0 = hist[2*tid], a1 = hist[2*tid+1];
  scanArr[tid] = a0 + a1;
  __syncthreads();
  for (int st = 1; st < 256; st <<= 1){
    int v = (tid >= st) ? scanArr[tid - st] : 0;
    __syncthreads();
    scanArr[tid] += v;
    __syncthreads();
  }
  int eb = tid ? scanArr[tid-1] : 0;
  pre[2*tid] = eb;        cur[2*tid] = eb;
  pre[2*tid+1] = eb + a0; cur[2*tid+1] = eb + a0;
  if (2*tid < NB && a0 > 0)   gbase[2*tid]   = atomicAdd(&gcursor[2*tid],   a0);
  if (2*tid+1 < NB && a1 > 0) gbase[2*tid+1] = atomicAdd(&gcursor[2*tid+1], a1);
  __syncthreads();
  for (int i = tid; i < cnt; i += 256){
    int s = ei[base + i];
    int d = ei[E + base + i];
    int lpos = atomicAdd(&cur[d >> 8], 1);
    stageS[lpos] = (uint)s; stageD[lpos] = (uint)d;
  }
  __syncthreads();
  for (int i = tid; i < cnt; i += 256){
    uint d = stageD[i];
    int b = d >> 8;
    tmp[gbase[b] + (i - pre[b])] = (stageS[i] << 8) | (d & 255u);
  }
}

__global__ __launch_bounds__(256) void k_csr(const uint* __restrict__ tmp,
                      const int* __restrict__ bucketBase,
                      int N, int NB, int* __restrict__ offsets, int* __restrict__ csr){
  int b = blockIdx.x;
  int nodeBase = b << 8;
  int nNodes = min(256, N - nodeBase);
  int eBeg = bucketBase[b], eEnd = bucketBase[b+1];
  __shared__ int deg[256], cur[256];
  int tid = threadIdx.x;
  deg[tid] = 0;
  __syncthreads();
  for (int e = eBeg + tid; e < eEnd; e += 256)
    atomicAdd(&deg[tmp[e] & 255u], 1);
  __syncthreads();
  cur[tid] = deg[tid];
  __syncthreads();
  for (int st = 1; st < 256; st <<= 1){
    int w = (tid >= st) ? cur[tid - st] : 0;
    __syncthreads();
    cur[tid] += w;
    __syncthreads();
  }
  int excl = tid ? cur[tid-1] : 0;
  __syncthreads();
  cur[tid] = excl;
  if (tid < nNodes) offsets[nodeBase + tid] = eBeg + excl;
  if (b == NB-1 && tid == 0) offsets[N] = eEnd;
  __syncthreads();
  for (int e = eBeg + tid; e < eEnd; e += 256){
    uint u = tmp[e];
    int lpos = atomicAdd(&cur[u & 255u], 1);
    csr[eBeg + lpos] = (int)(u >> 8);
  }
}

// ---------- W repack: W[K=128][M=NT*16] fp32 -> B-fragment-ordered bf16 ----------
// Wf[((t*4 + c)*64 + lane)*8 + j] = bf16(W[(c*32 + (lane>>4)*8 + j)*M + t*16 + (lane&15)])
template<int NT>
__global__ __launch_bounds__(256) void k_wrep(const float* __restrict__ W, ushort* __restrict__ Wf){
  int idx = blockIdx.x*256 + threadIdx.x;
  if (idx >= NT*4*64) return;
  int lane = idx & 63;
  int c = (idx >> 6) & 3;
  int t = idx >> 8;
  int col = t*16 + (lane & 15);
  int k0 = c*32 + (lane >> 4)*8;
  uint4 o;
  const float* p0 = W + (size_t)k0*(NT*16) + col;
  o.x = pk2(p0[0],          p0[NT*16]);
  o.y = pk2(p0[2*NT*16],    p0[3*NT*16]);
  o.z = pk2(p0[4*NT*16],    p0[5*NT*16]);
  o.w = pk2(p0[6*NT*16],    p0[7*NT*16]);
  *(uint4*)(Wf + (size_t)idx*8) = o;
}

// ---------- MFMA GEMM: Y[n, NT*16](bf16) = X[n,128] @ W ----------
// 16x16x32 bf16 MFMA. A frag: lane holds A[m=lane&15][k=(lane>>4)*8+j].
// B frag: lane holds B[k=(lane>>4)*8+j][n=lane&15] (from Wf repack).
// C/D: lane,reg r -> row=(lane>>4)*4+r, col=lane&15   [m89-verified]
template<int NT, bool A_F32>
__global__ __launch_bounds__(256) void k_mgemm(const void* __restrict__ Xv,
                     const ushort* __restrict__ Wf, ushort* __restrict__ Y, int n){
  constexpr int M = NT*16;
  int lane = threadIdx.x & 63;
  int l15 = lane & 15, q = lane >> 4;
  int wgid = blockIdx.x*4 + (threadIdx.x >> 6);
  int nchunks = (n + 15) >> 4;
  int stride = gridDim.x*4;

  bf16x8 bw[NT][4];
  #pragma unroll
  for (int t = 0; t < NT; t++)
    #pragma unroll
    for (int c = 0; c < 4; c++)
      bw[t][c] = *(const bf16x8*)(Wf + (size_t)(((t<<2)+c)*64 + lane)*8);

  int chunk = wgid;
  if (chunk >= nchunks) return;

  bf16x8 aCur[4], aNext[4];
  auto loadA = [&](int ck, bf16x8* a){
    int m = ck*16 + l15;
    if (m >= n) m = n - 1;
    if (A_F32){
      const float* X = (const float*)Xv + (size_t)m*128 + q*8;
      #pragma unroll
      for (int c = 0; c < 4; c++){
        float4 u0 = *(const float4*)(X + c*32);
        float4 u1 = *(const float4*)(X + c*32 + 4);
        uint4 pkd;
        pkd.x = pk2(u0.x, u0.y); pkd.y = pk2(u0.z, u0.w);
        pkd.z = pk2(u1.x, u1.y); pkd.w = pk2(u1.z, u1.w);
        union { uint4 u; bf16x8 v; } cv; cv.u = pkd;
        a[c] = cv.v;
      }
    } else {
      const ushort* X = (const ushort*)Xv + (size_t)m*128 + q*8;
      #pragma unroll
      for (int c = 0; c < 4; c++) a[c] = *(const bf16x8*)(X + c*32);
    }
  };

  loadA(chunk, aCur);
  while (true){
    int nx = chunk + stride;
    if (nx < nchunks) loadA(nx, aNext);
    f32x4 acc[NT];
    #pragma unroll
    for (int t = 0; t < NT; t++) acc[t] = (f32x4){0.f,0.f,0.f,0.f};
    #pragma unroll
    for (int c = 0; c < 4; c++)
      #pragma unroll
      for (int t = 0; t < NT; t++)
        acc[t] = __builtin_amdgcn_mfma_f32_16x16x32_bf16(aCur[c], bw[t][c], acc[t], 0, 0, 0);
    int rowb = chunk*16 + q*4;
    #pragma unroll
    for (int t = 0; t < NT; t++)
      #pragma unroll
      for (int r = 0; r < 4; r++){
        int row = rowb + r;
        if (row < n) Y[(size_t)row*M + t*16 + l15] = f2bf(acc[t][r]);
      }
    if (nx >= nchunks) break;
    chunk = nx;
    #pragma unroll
    for (int c = 0; c < 4; c++) aCur[c] = aNext[c];
  }
}

// ---------- attention coefficients (reads bf16 h) ----------
__global__ __launch_bounds__(256) void k_attn(const ushort* __restrict__ Hb, const float* __restrict__ a_s,
                     const float* __restrict__ a_d, float* __restrict__ asrc, float* __restrict__ adst,
                     int n, int H, int M){
  int idx = blockIdx.x*256 + threadIdx.x;
  if (idx >= n*H) return;
  int node = idx / H, h = idx - node*H;
  const uint4* r4 = (const uint4*)(Hb + (size_t)node*M + h*32);
  const float* as = a_s + h*32;
  const float* ad = a_d + h*32;
  float s1 = 0.f, s2 = 0.f;
  #pragma unroll
  for (int i = 0; i < 4; i++){
    uint4 qv = r4[i];
    uint w[4] = {qv.x, qv.y, qv.z, qv.w};
    #pragma unroll
    for (int j = 0; j < 4; j++){
      float2 f = bfpair(w[j]);
      int c = i*8 + j*2;
      s1 += f.x*as[c] + f.y*as[c+1];
      s2 += f.x*ad[c] + f.y*ad[c+1];
    }
  }
  asrc[idx] = s1; adst[idx] = s2;
}

// ---------- per-dst softmax-weighted aggregation + bias + ELU ----------
template<int HC, bool OUT_BF16>
__global__ __launch_bounds__(256) void k_agg(const ushort* __restrict__ Hb, const float* __restrict__ asrc,
                    const float* __restrict__ adst, const int* __restrict__ offsets,
                    const int* __restrict__ csr_src, const float* __restrict__ bias,
                    void* __restrict__ Out, int n){
  constexpr int H = HC/32;
  constexpr int PAIRS = HC/2;
  int gid = blockIdx.x*256 + threadIdx.x;
  int wave = gid >> 6;
  int lane = threadIdx.x & 63;
  int node, up;
  if (HC == 128){ node = wave;                 up = lane;      }
  else          { node = wave*4 + (lane >> 4); up = lane & 15; }
  if (node >= n) return;
  const int ch = up*2;
  const int h0 = ch >> 5;
  const uint* rows = (const uint*)Hb;
  float ad = adst[node*H + h0];
  float acc0 = 0.f, acc1 = 0.f, den = 0.f;
  {
    float w = __expf(leaky(asrc[node*H + h0] + ad));
    float2 f = bfpair(rows[(size_t)node*PAIRS + up]);
    den += w; acc0 += w*f.x; acc1 += w*f.y;
  }
  int j = offsets[node], end = offsets[node+1];
  for (; j + 4 <= end; j += 4){
    int s0 = csr_src[j], s1 = csr_src[j+1], s2 = csr_src[j+2], s3 = csr_src[j+3];
    if (HC == 128){
      s0 = __builtin_amdgcn_readfirstlane(s0);
      s1 = __builtin_amdgcn_readfirstlane(s1);
      s2 = __builtin_amdgcn_readfirstlane(s2);
      s3 = __builtin_amdgcn_readfirstlane(s3);
    }
    float e0 = asrc[s0*H + h0], e1 = asrc[s1*H + h0], e2 = asrc[s2*H + h0], e3 = asrc[s3*H + h0];
    uint r0 = rows[(size_t)s0*PAIRS + up];
    uint r1 = rows[(size_t)s1*PAIRS + up];
    uint r2 = rows[(size_t)s2*PAIRS + up];
    uint r3 = rows[(size_t)s3*PAIRS + up];
    float w0 = __expf(leaky(e0 + ad));
    float w1 = __expf(leaky(e1 + ad));
    float w2 = __expf(leaky(e2 + ad));
    float w3 = __expf(leaky(e3 + ad));
    float2 f0 = bfpair(r0), f1 = bfpair(r1), f2 = bfpair(r2), f3 = bfpair(r3);
    den  += (w0 + w1) + (w2 + w3);
    acc0 += w0*f0.x + w1*f1.x + w2*f2.x + w3*f3.x;
    acc1 += w0*f0.y + w1*f1.y + w2*f2.y + w3*f3.y;
  }
  for (; j < end; j++){
    int s = csr_src[j];
    if (HC == 128) s = __builtin_amdgcn_readfirstlane(s);
    float w = __expf(leaky(asrc[s*H + h0] + ad));
    float2 f = bfpair(rows[(size_t)s*PAIRS + up]);
    den += w; acc0 += w*f.x; acc1 += w*f.y;
  }
  float inv = 1.f/(den + 1e-16f);
  float ox = elu(acc0*inv + bias[ch]);
  float oy = elu(acc1*inv + bias[ch+1]);
  if (OUT_BF16){
    ((uint*)Out)[(size_t)node*PAIRS + up] = pk2(ox, oy);
  } else {
    *(float2*)((float*)Out + (size_t)node*HC + ch) = make_float2(ox, oy);
  }
}

// ---------- readout ----------
__global__ __launch_bounds__(256) void k_bounds(const int* __restrict__ batch, int n, int G,
                                                int* __restrict__ gstart){
  int i = blockIdx.x*256 + threadIdx.x;
  if (i >= n) return;
  int b = batch[i];
  int bp = (i > 0) ? batch[i-1] : -1;
  for (int g = bp + 1; g <= b; g++) gstart[g] = i;
  if (i == n-1){
    for (int g = b + 1; g <= G; g++) gstart[g] = n;
  }
}

__global__ __launch_bounds__(256) void k_pool2(const float* __restrict__ H3,
                     const int* __restrict__ gstart, const float* __restrict__ fcw,
                     const float* __restrict__ fcb, float* __restrict__ out, int G){
  int g = blockIdx.x;
  int s0 = gstart[g], s1 = gstart[g+1];
  int tid = threadIdx.x;
  int c = tid & 31, r = tid >> 5;
  float sum = 0.f;
  for (int i = s0 + r; i < s1; i += 8)
    sum += H3[(size_t)i*32 + c];
  __shared__ float sh[8][32];
  sh[r][c] = sum;
  __syncthreads();
  if (tid < 32){
    float t = 0.f;
    #pragma unroll
    for (int k = 0; k < 8; k++) t += sh[k][tid];
    t *= fcw[tid];
    #pragma unroll
    for (int off = 16; off; off >>= 1) t += __shfl_down(t, off, 32);
    if (tid == 0){
      float cnt = (float)(s1 - s0); if (cnt < 1.f) cnt = 1.f;
      out[g] = t/cnt + fcb[0];
    }
  }
}

extern "C" void kernel_launch(void* const* d_in, const int* in_sizes, int n_in,
                              void* d_out, int out_size, void* d_ws, size_t ws_size,
                              hipStream_t stream){
  const float* x    = (const float*)d_in[0];
  const int*   ei   = (const int*)d_in[1];
  const int*   batch= (const int*)d_in[2];
  const float* W1   = (const float*)d_in[3];
  const float* as1  = (const float*)d_in[4];
  const float* ad1  = (const float*)d_in[5];
  const float* b1   = (const float*)d_in[6];
  const float* W2   = (const float*)d_in[7];
  const float* as2  = (const float*)d_in[8];
  const float* ad2  = (const float*)d_in[9];
  const float* b2   = (const float*)d_in[10];
  const float* W3   = (const float*)d_in[11];
  const float* as3  = (const float*)d_in[12];
  const float* ad3  = (const float*)d_in[13];
  const float* b3   = (const float*)d_in[14];
  const float* fcw  = (const float*)d_in[15];
  const float* fcb  = (const float*)d_in[16];
  float* out = (float*)d_out;

  const int N = in_sizes[0] / 128;
  const int E = in_sizes[1] / 2;
  const int G = out_size;
  const int NB = (N + 255) >> 8;

  char* p = (char*)d_ws;
  auto alloc = [&](size_t bytes) -> void* {
    void* r = (void*)p;
    p += (bytes + 255) & ~(size_t)255;
    return r;
  };
  ushort* bufH   = (ushort*)alloc((size_t)N*128*sizeof(ushort));  // GEMM out (bf16)
  ushort* aggB   = (ushort*)alloc((size_t)N*128*sizeof(ushort));  // agg out L1/L2 (bf16)
  float*  bufA32 = (float*)alloc((size_t)N*32*sizeof(float));     // agg out L3 (fp32)
  float*  asrc   = (float*)alloc((size_t)N*4*sizeof(float));
  float*  adst   = (float*)alloc((size_t)N*4*sizeof(float));
  int*    offsets= (int*)alloc((size_t)(N+1)*sizeof(int));
  int*    csr    = (int*)alloc((size_t)E*sizeof(int));
  uint*   tmp    = (uint*)alloc((size_t)E*sizeof(uint));
  int*    bCount = (int*)alloc(512*sizeof(int));
  int*    bBase  = (int*)alloc(520*sizeof(int));
  int*    gcursor= (int*)alloc(512*sizeof(int));
  int*    gstart = (int*)alloc((size_t)(G+1)*sizeof(int));
  ushort* Wf1    = (ushort*)alloc(8*4*64*8*sizeof(ushort));
  ushort* Wf2    = (ushort*)alloc(8*4*64*8*sizeof(ushort));
  ushort* Wf3    = (ushort*)alloc(2*4*64*8*sizeof(ushort));

  hipMemsetAsync(bCount, 0, 512*sizeof(int), stream);

  // W repacks (independent, cheap)
  k_wrep<8><<<8, 256, 0, stream>>>(W1, Wf1);
  k_wrep<8><<<8, 256, 0, stream>>>(W2, Wf2);
  k_wrep<2><<<2, 256, 0, stream>>>(W3, Wf3);

  // CSR build
  k_histA<<<(E+2047)/2048, 256, 0, stream>>>(ei, E, bCount);
  k_scanB<<<1, 256, 0, stream>>>(bCount, NB, bBase, gcursor, E);
  k_scatA<<<(E+CHUNK-1)/CHUNK, 256, 0, stream>>>(ei, E, NB, gcursor, tmp);
  k_csr<<<NB, 256, 0, stream>>>(tmp, bBase, N, NB, offsets, csr);
  k_bounds<<<(N+255)/256, 256, 0, stream>>>(batch, N, G, gstart);

  const int GB = 512;   // gemm blocks (grid-stride; ~3 chunks/wave, W frags amortized)
  // layer 1
  k_mgemm<8, true ><<<GB, 256, 0, stream>>>(x, Wf1, bufH, N);
  k_attn<<<(N*4+255)/256, 256, 0, stream>>>(bufH, as1, ad1, asrc, adst, N, 4, 128);
  k_agg<128, true><<<(N*64+255)/256, 256, 0, stream>>>(bufH, asrc, adst, offsets, csr, b1, aggB, N);
  // layer 2
  k_mgemm<8, false><<<GB, 256, 0, stream>>>(aggB, Wf2, bufH, N);
  k_attn<<<(N*4+255)/256, 256, 0, stream>>>(bufH, as2, ad2, asrc, adst, N, 4, 128);
  k_agg<128, true><<<(N*64+255)/256, 256, 0, stream>>>(bufH, asrc, adst, offsets, csr, b2, aggB, N);
  // layer 3
  k_mgemm<2, false><<<GB, 256, 0, stream>>>(aggB, Wf3, bufH, N);
  k_attn<<<(N+255)/256, 256, 0, stream>>>(bufH, as3, ad3, asrc, adst, N, 1, 32);
  int waves3 = (N + 3)/4;
  k_agg<32, false><<<(waves3*64 + 255)/256, 256, 0, stream>>>(bufH, asrc, adst, offsets, csr, b3, bufA32, N);
  // readout
  k_pool2<<<G, 256, 0, stream>>>(bufA32, gstart, fcw, fcb, out, G);
}